// Round 11
// baseline (3435.655 us; speedup 1.0000x reference)
//
#include <hip/hip_runtime.h>
#include <hip/hip_bf16.h>
#include <math.h>

// ---- problem constants ----
#define D_MODEL 2048
#define SEQ     2048
#define BATCH   2
#define NHEAD   16
#define DK      128
#define DFF     8192
#define MROWS   (BATCH*SEQ)   // 4096 rows

typedef short short8 __attribute__((ext_vector_type(8)));   // 8 bf16 in 4 VGPRs
typedef float f32x4  __attribute__((ext_vector_type(4)));

__device__ __forceinline__ short f2bf(float f) {
  union { __hip_bfloat16 b; short s; } u;
  u.b = __float2bfloat16(f);
  return u.s;
}
__device__ __forceinline__ float bf2f(short s) {
  union { unsigned u; float f; } u;
  u.u = ((unsigned)(unsigned short)s) << 16;
  return u.f;
}

#define MF(a, b, c) __builtin_amdgcn_mfma_f32_16x16x32_bf16(a, b, c, 0, 0, 0)

// ---------------- RMSNorm: fp32 in -> bf16 out ----------------
__global__ __launch_bounds__(256) void rmsnorm_k(const float* __restrict__ x,
                                                 const float* __restrict__ g,
                                                 short* __restrict__ o) {
  const int row = blockIdx.x;
  const int t = threadIdx.x;
  const float4* xr = (const float4*)(x + (size_t)row * D_MODEL);
  const float4* gr = (const float4*)g;
  float4 v0 = xr[2*t], v1 = xr[2*t+1];
  float s = v0.x*v0.x + v0.y*v0.y + v0.z*v0.z + v0.w*v0.w
          + v1.x*v1.x + v1.y*v1.y + v1.z*v1.z + v1.w*v1.w;
  #pragma unroll
  for (int off = 1; off < 64; off <<= 1) s += __shfl_xor(s, off);
  __shared__ float red[4];
  if ((t & 63) == 0) red[t >> 6] = s;
  __syncthreads();
  float tot = red[0] + red[1] + red[2] + red[3];
  float inv = rsqrtf(tot * (1.0f / D_MODEL) + 1e-5f);
  float4 g0 = gr[2*t], g1v = gr[2*t+1];
  short8 ov;
  ov[0] = f2bf(v0.x * inv * g0.x);
  ov[1] = f2bf(v0.y * inv * g0.y);
  ov[2] = f2bf(v0.z * inv * g0.z);
  ov[3] = f2bf(v0.w * inv * g0.w);
  ov[4] = f2bf(v1.x * inv * g1v.x);
  ov[5] = f2bf(v1.y * inv * g1v.y);
  ov[6] = f2bf(v1.z * inv * g1v.z);
  ov[7] = f2bf(v1.w * inv * g1v.w);
  *((short8*)(o + (size_t)row * D_MODEL) + t) = ov;
}

// ---------------- fp32 -> bf16 convert (weights, one-time) ----------------
__global__ __launch_bounds__(256) void f2b_k(const float* __restrict__ src,
                                             short* __restrict__ dst, int n8) {
  int i = blockIdx.x * 256 + threadIdx.x;
  if (i >= n8) return;
  const float4* s4 = (const float4*)src + 2 * (size_t)i;
  float4 a = s4[0], b = s4[1];
  short8 o = { f2bf(a.x), f2bf(a.y), f2bf(a.z), f2bf(a.w),
               f2bf(b.x), f2bf(b.y), f2bf(b.z), f2bf(b.w) };
  *((short8*)dst + i) = o;
}

// ---------------- split-K combine: o = bf16(p0) + bf16(p1) + fp32(r) ----------------
__global__ __launch_bounds__(256) void combine_bb(const short* __restrict__ p0,
                                                  const short* __restrict__ p1,
                                                  const float* __restrict__ r,
                                                  float* __restrict__ o, int n8) {
  int i = blockIdx.x * 256 + threadIdx.x;
  if (i >= n8) return;
  short8 a = ((const short8*)p0)[i];
  short8 b = ((const short8*)p1)[i];
  float4 r0 = ((const float4*)r)[2 * (size_t)i];
  float4 r1 = ((const float4*)r)[2 * (size_t)i + 1];
  float4 o0, o1;
  o0.x = bf2f(a[0]) + bf2f(b[0]) + r0.x;
  o0.y = bf2f(a[1]) + bf2f(b[1]) + r0.y;
  o0.z = bf2f(a[2]) + bf2f(b[2]) + r0.z;
  o0.w = bf2f(a[3]) + bf2f(b[3]) + r0.w;
  o1.x = bf2f(a[4]) + bf2f(b[4]) + r1.x;
  o1.y = bf2f(a[5]) + bf2f(b[5]) + r1.y;
  o1.z = bf2f(a[6]) + bf2f(b[6]) + r1.z;
  o1.w = bf2f(a[7]) + bf2f(b[7]) + r1.w;
  ((float4*)o)[2 * (size_t)i]     = o0;
  ((float4*)o)[2 * (size_t)i + 1] = o1;
}

// ---- fused: x2 = bf16(p0)+bf16(p1)+x (fp32, ->out) ; xn = rmsnorm(x2, g) bf16 ----
// one block per row (256 thr x 8 elems = 2048)
__global__ __launch_bounds__(256) void combine_rms(const short* __restrict__ p0,
                                                   const short* __restrict__ p1,
                                                   const float* __restrict__ xres,
                                                   const float* __restrict__ g,
                                                   float* __restrict__ out,
                                                   short* __restrict__ xn) {
  const int row = blockIdx.x;
  const int t = threadIdx.x;
  const size_t b8 = (size_t)row * (D_MODEL / 8) + t;
  short8 a = ((const short8*)p0)[b8];
  short8 b = ((const short8*)p1)[b8];
  float4 r0 = ((const float4*)xres)[2 * b8];
  float4 r1 = ((const float4*)xres)[2 * b8 + 1];
  float v[8];
  v[0] = bf2f(a[0]) + bf2f(b[0]) + r0.x;
  v[1] = bf2f(a[1]) + bf2f(b[1]) + r0.y;
  v[2] = bf2f(a[2]) + bf2f(b[2]) + r0.z;
  v[3] = bf2f(a[3]) + bf2f(b[3]) + r0.w;
  v[4] = bf2f(a[4]) + bf2f(b[4]) + r1.x;
  v[5] = bf2f(a[5]) + bf2f(b[5]) + r1.y;
  v[6] = bf2f(a[6]) + bf2f(b[6]) + r1.z;
  v[7] = bf2f(a[7]) + bf2f(b[7]) + r1.w;
  float4 o0 = {v[0], v[1], v[2], v[3]}, o1 = {v[4], v[5], v[6], v[7]};
  ((float4*)out)[2 * b8]     = o0;
  ((float4*)out)[2 * b8 + 1] = o1;
  float s = 0.f;
  #pragma unroll
  for (int j = 0; j < 8; ++j) s += v[j] * v[j];
  #pragma unroll
  for (int off = 1; off < 64; off <<= 1) s += __shfl_xor(s, off);
  __shared__ float red[4];
  if ((t & 63) == 0) red[t >> 6] = s;
  __syncthreads();
  float tot = red[0] + red[1] + red[2] + red[3];
  float inv = rsqrtf(tot * (1.0f / D_MODEL) + 1e-5f);
  float4 g0 = ((const float4*)g)[2 * t], g1v = ((const float4*)g)[2 * t + 1];
  short8 ov;
  ov[0] = f2bf(v[0] * inv * g0.x);
  ov[1] = f2bf(v[1] * inv * g0.y);
  ov[2] = f2bf(v[2] * inv * g0.z);
  ov[3] = f2bf(v[3] * inv * g0.w);
  ov[4] = f2bf(v[4] * inv * g1v.x);
  ov[5] = f2bf(v[5] * inv * g1v.y);
  ov[6] = f2bf(v[6] * inv * g1v.z);
  ov[7] = f2bf(v[7] * inv * g1v.w);
  ((short8*)xn)[b8] = ov;
}

// ======== 128x128 reg-prefetch GEMM, 4 blocks/CU, latency-hidden staging ========
// C[M,N] = A[M,K](bf16) * B[N,K](bf16)^T. 256 thr = 4 waves (2M x 2N), wave 64x64.
// Single 32 KB LDS buffer (4 blocks/CU) + DOUBLE-BUFFER THROUGH REGISTERS:
// regs hold tile T+1 (8x uint4, loaded during compute of T-1/T); after the
// post-compute barrier: ds_write regs -> LDS (swizzled), issue loads T+2 -> regs.
// Compiler's auto-vmcnt lands before the ds_write (i.e. AFTER compute) -> global
// latency hidden under a full tile of MFMA. Both-sides swizzle: write-side XOR
// ((row&7)*8 shorts) + read-side XOR -> 0 bank conflicts (R10-verified mapping);
// global loads fully linear. EPI: 0 bf16; 1 GELU bf16; 2 +resid fp32.
// SPLIT: split-K x2, bf16 partials at Cv + ks*M*N.
template<int EPI, int SPLIT>
__global__ __launch_bounds__(256, 4) void gemm128r(const short* __restrict__ A,
                                                   const short* __restrict__ Bp,
                                                   void* Cv,
                                                   const float* __restrict__ resid,
                                                   int M, int N, int Kloop,
                                                   int lda, int nbx) {
  __shared__ __align__(16) short As[128 * 64];   // 16 KB
  __shared__ __align__(16) short Bs[128 * 64];   // 16 KB
  const int nk = Kloop >> 6;
  const int cpx = gridDim.x >> 3;                // grid % 8 == 0 (bijective XCD swizzle)
  const int lin = (blockIdx.x & 7) * cpx + (blockIdx.x >> 3);
  const int bx = lin % nbx;
  int row2 = lin / nbx, by, ks = 0;
  if (SPLIT) { ks = row2 & 1; by = row2 >> 1; } else { by = row2; }
  const int m0 = bx * 128, n0 = by * 128;
  if (SPLIT) { A += (size_t)ks * Kloop; Bp += (size_t)ks * Kloop; }

  const int t = threadIdx.x, w = t >> 6, lane = t & 63, lr = lane & 15, lg = lane >> 4;
  const int wm = w >> 1, wn = w & 1;

  // staging: thread t -> rows r+32i (i=0..3), 16B chunk c8; LINEAR global reads
  const int r = t >> 3, c8 = t & 7;
  const short* pA = A  + (size_t)(m0 + r) * lda + c8 * 8;
  const short* pB = Bp + (size_t)(n0 + r) * lda + c8 * 8;
  const size_t l32 = (size_t)32 * lda;
  const int wsw = (c8 ^ (r & 7)) * 8;            // swizzled col offset (shorts); (r+32i)&7==r&7

  uint4 ra[4], rb[4];
#define LOADT(T_) { \
    _Pragma("unroll") for (int i_ = 0; i_ < 4; ++i_) \
      ra[i_] = *(const uint4*)(pA + (size_t)(T_) * 64 + i_ * l32); \
    _Pragma("unroll") for (int i_ = 0; i_ < 4; ++i_) \
      rb[i_] = *(const uint4*)(pB + (size_t)(T_) * 64 + i_ * l32); }
#define STORET() { \
    _Pragma("unroll") for (int i_ = 0; i_ < 4; ++i_) \
      *(uint4*)&As[(r + 32 * i_) * 64 + wsw] = ra[i_]; \
    _Pragma("unroll") for (int i_ = 0; i_ < 4; ++i_) \
      *(uint4*)&Bs[(r + 32 * i_) * 64 + wsw] = rb[i_]; }

  f32x4 acc[4][4];
  const f32x4 z4 = {0.f, 0.f, 0.f, 0.f};
  #pragma unroll
  for (int m = 0; m < 4; ++m)
    #pragma unroll
    for (int n = 0; n < 4; ++n) acc[m][n] = z4;

  const int rsw = (lr & 7) << 3;                 // lane-constant read swizzle (shorts)

  // prologue: tile 0 -> LDS; tile 1 -> regs (stays in flight across compute 0)
  LOADT(0);
  STORET();                                      // compiler waits vmcnt here
  if (nk > 1) LOADT(1);
  __syncthreads();

  for (int T = 0; T < nk; ++T) {
    // ---- compute tile T (k-half x n-group structure caps live VGPRs) ----
    #pragma unroll
    for (int kk = 0; kk < 2; ++kk) {
      short8 af[4];
      #pragma unroll
      for (int m = 0; m < 4; ++m) {
        int ar = wm * 64 + m * 16 + lr;
        af[m] = *(const short8*)&As[ar * 64 + ((kk * 32 + lg * 8) ^ rsw)];
      }
      #pragma unroll
      for (int n = 0; n < 4; ++n) {
        int br = wn * 64 + n * 16 + lr;
        short8 bf = *(const short8*)&Bs[br * 64 + ((kk * 32 + lg * 8) ^ rsw)];
        #pragma unroll
        for (int m = 0; m < 4; ++m) acc[m][n] = MF(af[m], bf, acc[m][n]);
      }
    }
    if (T + 1 < nk) {
      __syncthreads();     // all waves done reading tile T
      STORET();            // tile T+1 regs -> LDS (vmcnt wait was hidden under compute)
      if (T + 2 < nk) LOADT(T + 2);
      __syncthreads();     // writes visible before next compute
    }
  }
#undef LOADT
#undef STORET

  // ---- epilogue ----
  short* Cs = (short*)Cv;
  if (SPLIT) Cs += (size_t)ks * ((size_t)M * N);
  #pragma unroll
  for (int m = 0; m < 4; ++m)
    #pragma unroll
    for (int n = 0; n < 4; ++n)
      #pragma unroll
      for (int rr = 0; rr < 4; ++rr) {
        int row = m0 + wm * 64 + m * 16 + lg * 4 + rr;
        int col = n0 + wn * 64 + n * 16 + lr;
        size_t idx = (size_t)row * N + col;
        float vv = acc[m][n][rr];
        if (EPI == 0) {
          Cs[idx] = f2bf(vv);
        } else if (EPI == 1) {
          float gl = 0.5f * vv * (1.0f + erff(vv * 0.70710678118654752f));
          ((short*)Cv)[idx] = f2bf(gl);
        } else {
          ((float*)Cv)[idx] = vv + resid[idx];
        }
      }
}

// ---------------- V transpose: qkv[.., v cols] -> vt[b][h][d][s] ----------------
__global__ __launch_bounds__(256) void vtrans(const short* __restrict__ QKV,
                                              short* __restrict__ VT) {
  const int st = blockIdx.x;   // s tile of 64
  const int bh = blockIdx.y;
  const int b = bh >> 4, h = bh & 15;
  const int t = threadIdx.x;
  __shared__ __align__(16) short T[64 * 128];
  const short* Vsrc = QKV + ((size_t)b * SEQ) * 6144 + 2 * D_MODEL + h * DK;
  {
    int r = t >> 4, c = (t & 15) * 8;
    #pragma unroll
    for (int i = 0; i < 4; ++i) {
      int rr = r + 16 * i;
      uint4 vv = *(const uint4*)(Vsrc + (size_t)(st * 64 + rr) * 6144 + c);
      *(uint4*)&T[rr * 128 + (c ^ (((rr >> 3) & 7) << 3))] = vv;
    }
  }
  __syncthreads();
  short* dst = VT + ((size_t)bh * DK) * SEQ + st * 64;
  {
    int c2 = (t & 7) * 8;
    #pragma unroll
    for (int i = 0; i < 4; ++i) {
      int d = (t >> 3) + 32 * i;
      short8 ov;
      #pragma unroll
      for (int j = 0; j < 8; ++j)
        ov[j] = T[(c2 + j) * 128 + (d ^ ((((c2 + j) >> 3) & 7) << 3))];
      *(short8*)(dst + (size_t)d * SEQ + c2) = ov;
    }
  }
}

// ---------------- Flash attention v3 (round-4 verified) ----------------
__global__ __launch_bounds__(512, 2) void attn3(const short* __restrict__ QKV,
                                                const short* __restrict__ VT,
                                                short* __restrict__ O) {
  const float SC = 0.12751743f;   // (1/sqrt(128)) * log2(e)
  const int a = blockIdx.x, bh = blockIdx.y;
  const int b = bh >> 4, h = bh & 15;
  const int t = threadIdx.x, w = t >> 6, lane = t & 63, lr = lane & 15, lg = lane >> 4;
  const short* Qp = QKV + ((size_t)b * SEQ) * 6144 + h * DK;
  const short* Kp = Qp + D_MODEL;
  const short* Vp = VT + ((size_t)bh * DK) * SEQ;   // [d][s]
  __shared__ __align__(16) short Ks[2][64 * 128];
  __shared__ __align__(16) short Vs[2][128 * 64];
  __shared__ __align__(16) short Ps[8][16][72];

  const int krr = t >> 4, kcc = (t & 15) * 8;
  const int vdd = t >> 3, vcc = (t & 7) * 8;
  const f32x4 z4 = {0.f, 0.f, 0.f, 0.f};

  for (int sub = 0; sub < 2; ++sub) {
    const int ts = sub ? (15 - a) : a;
    const int nt = 2 * ts + 2;
    const int qrow0 = ts * 128 + w * 16;

    short8 qf[4];
    #pragma unroll
    for (int ki = 0; ki < 4; ++ki)
      qf[ki] = *(const short8*)(Qp + (size_t)(qrow0 + lr) * 6144 + ki * 32 + lg * 8);

    f32x4 acc[8];
    #pragma unroll
    for (int nd = 0; nd < 8; ++nd) acc[nd] = z4;
    float mrow[4], lsum[4];
    #pragma unroll
    for (int r = 0; r < 4; ++r) { mrow[r] = -INFINITY; lsum[r] = 0.f; }

    uint4 krg[2], vrg[2];
    #pragma unroll
    for (int i = 0; i < 2; ++i) {
      krg[i] = *(const uint4*)(Kp + (size_t)(krr + 32 * i) * 6144 + kcc);
      vrg[i] = *(const uint4*)(Vp + (size_t)(vdd + 64 * i) * SEQ + vcc);
    }
    __syncthreads();
    #pragma unroll
    for (int i = 0; i < 2; ++i) {
      int r = krr + 32 * i;
      *(uint4*)&Ks[0][(r * 128 + kcc) ^ ((r & 7) << 3)] = krg[i];
      int d = vdd + 64 * i;
      *(uint4*)&Vs[0][(d * 64 + vcc) ^ ((d & 7) << 3)] = vrg[i];
    }
    __syncthreads();

    int cur = 0;
    for (int tt = 0; tt < nt; ++tt) {
      const bool pre = (tt + 1 < nt);
      if (pre) {
        #pragma unroll
        for (int i = 0; i < 2; ++i) {
          krg[i] = *(const uint4*)(Kp + (size_t)((tt + 1) * 64 + krr + 32 * i) * 6144 + kcc);
          vrg[i] = *(const uint4*)(Vp + (size_t)(vdd + 64 * i) * SEQ + (tt + 1) * 64 + vcc);
        }
      }

      f32x4 sf[4] = {z4, z4, z4, z4};
      #pragma unroll
      for (int ki = 0; ki < 4; ++ki) {
        #pragma unroll
        for (int nk = 0; nk < 4; ++nk) {
          int rr = nk * 16 + lr;
          short8 kf = *(const short8*)&Ks[cur][(rr * 128 + ki * 32 + lg * 8) ^ ((rr & 7) << 3)];
          sf[nk] = MF(qf[ki], kf, sf[nk]);
        }
      }

      const bool diag = (tt * 64 + 63 > qrow0);
      #pragma unroll
      for (int r = 0; r < 4; ++r) {
        int qg = qrow0 + lg * 4 + r;
        float s0 = sf[0][r] * SC, s1 = sf[1][r] * SC, s2 = sf[2][r] * SC, s3 = sf[3][r] * SC;
        if (diag) {
          int c0 = tt * 64 + lr;
          s0 = (c0      <= qg) ? s0 : -3.0e38f;
          s1 = (c0 + 16 <= qg) ? s1 : -3.0e38f;
          s2 = (c0 + 32 <= qg) ? s2 : -3.0e38f;
          s3 = (c0 + 48 <= qg) ? s3 : -3.0e38f;
        }
        float mx = fmaxf(fmaxf(s0, s1), fmaxf(s2, s3));
        mx = fmaxf(mx, __shfl_xor(mx, 1));
        mx = fmaxf(mx, __shfl_xor(mx, 2));
        mx = fmaxf(mx, __shfl_xor(mx, 4));
        mx = fmaxf(mx, __shfl_xor(mx, 8));
        float mnew = fmaxf(mrow[r], mx);
        float alpha = exp2f(mrow[r] - mnew);
        mrow[r] = mnew;
        float p0 = exp2f(s0 - mnew), p1 = exp2f(s1 - mnew),
              p2 = exp2f(s2 - mnew), p3 = exp2f(s3 - mnew);
        lsum[r] = lsum[r] * alpha + ((p0 + p1) + (p2 + p3));
        #pragma unroll
        for (int nd = 0; nd < 8; ++nd) acc[nd][r] *= alpha;
        short* pr = &Ps[w][lg * 4 + r][0];
        pr[lr]      = f2bf(p0);
        pr[16 + lr] = f2bf(p1);
        pr[32 + lr] = f2bf(p2);
        pr[48 + lr] = f2bf(p3);
      }
      asm volatile("s_waitcnt lgkmcnt(0)" ::: "memory");
      __builtin_amdgcn_sched_barrier(0);

      short8 pf0 = *(const short8*)&Ps[w][lr][lg * 8];
      short8 pf1 = *(const short8*)&Ps[w][lr][32 + lg * 8];
      #pragma unroll
      for (int nd = 0; nd < 8; ++nd) {
        int rr = nd * 16 + lr;
        short8 vf0 = *(const short8*)&Vs[cur][(rr * 64 + lg * 8) ^ ((rr & 7) << 3)];
        short8 vf1 = *(const short8*)&Vs[cur][(rr * 64 + 32 + lg * 8) ^ ((rr & 7) << 3)];
        acc[nd] = MF(pf0, vf0, acc[nd]);
        acc[nd] = MF(pf1, vf1, acc[nd]);
      }
      __syncthreads();
      if (pre) {
        #pragma unroll
        for (int i = 0; i < 2; ++i) {
          int r = krr + 32 * i;
          *(uint4*)&Ks[cur ^ 1][(r * 128 + kcc) ^ ((r & 7) << 3)] = krg[i];
          int d = vdd + 64 * i;
          *(uint4*)&Vs[cur ^ 1][(d * 64 + vcc) ^ ((d & 7) << 3)] = vrg[i];
        }
      }
      __syncthreads();
      cur ^= 1;
    }

    float inv[4];
    #pragma unroll
    for (int r = 0; r < 4; ++r) {
      float ls = lsum[r];
      ls += __shfl_xor(ls, 1);
      ls += __shfl_xor(ls, 2);
      ls += __shfl_xor(ls, 4);
      ls += __shfl_xor(ls, 8);
      inv[r] = 1.0f / ls;
    }
    #pragma unroll
    for (int nd = 0; nd < 8; ++nd)
      #pragma unroll
      for (int r = 0; r < 4; ++r) {
        int row = qrow0 + lg * 4 + r;
        O[(size_t)(b * SEQ + row) * D_MODEL + h * DK + nd * 16 + lr] = f2bf(acc[nd][r] * inv[r]);
      }
  }
}

// ======== FALLBACK PATH (round-2 verified kernels) ========
template<int EPI>
__global__ __launch_bounds__(256) void gemm_bt(const short* __restrict__ A,
                                               const float* __restrict__ B,
                                               void* Cv,
                                               const float* resid,
                                               int M, int N, int K) {
  __shared__ __align__(16) short As[128][72];
  __shared__ __align__(16) short Bs[128][72];
  const int t = threadIdx.x;
  const int m0 = blockIdx.x * 128, n0 = blockIdx.y * 128;
  const int wave = t >> 6, lane = t & 63, lr = lane & 15, lg = lane >> 4;
  const int wr = (wave >> 1) * 64, wc = (wave & 1) * 64;

  f32x4 acc[4][4];
  const f32x4 z4 = {0.f, 0.f, 0.f, 0.f};
  #pragma unroll
  for (int m = 0; m < 4; ++m)
    #pragma unroll
    for (int n = 0; n < 4; ++n) acc[m][n] = z4;

  int ar[4], ac[4];
  #pragma unroll
  for (int i = 0; i < 4; ++i) { int u = t + 256*i; ar[i] = u >> 3; ac[i] = (u & 7) * 8; }

  for (int k0 = 0; k0 < K; k0 += 64) {
    #pragma unroll
    for (int i = 0; i < 4; ++i) {
      uint4 va = *(const uint4*)(A + (size_t)(m0 + ar[i]) * K + k0 + ac[i]);
      *(uint4*)&As[ar[i]][ac[i]] = va;
    }
    #pragma unroll
    for (int i = 0; i < 4; ++i) {
      const float4* bp = (const float4*)(B + (size_t)(n0 + ar[i]) * K + k0 + ac[i]);
      float4 b0 = bp[0], b1 = bp[1];
      short8 pb = { f2bf(b0.x), f2bf(b0.y), f2bf(b0.z), f2bf(b0.w),
                    f2bf(b1.x), f2bf(b1.y), f2bf(b1.z), f2bf(b1.w) };
      *(short8*)&Bs[ar[i]][ac[i]] = pb;
    }
    __syncthreads();
    #pragma unroll
    for (int kk = 0; kk < 64; kk += 32) {
      short8 af[4], bfr[4];
      #pragma unroll
      for (int m = 0; m < 4; ++m) af[m]  = *(const short8*)&As[wr + m*16 + lr][kk + lg*8];
      #pragma unroll
      for (int n = 0; n < 4; ++n) bfr[n] = *(const short8*)&Bs[wc + n*16 + lr][kk + lg*8];
      #pragma unroll
      for (int m = 0; m < 4; ++m)
        #pragma unroll
        for (int n = 0; n < 4; ++n)
          acc[m][n] = MF(af[m], bfr[n], acc[m][n]);
    }
    __syncthreads();
  }

  #pragma unroll
  for (int m = 0; m < 4; ++m)
    #pragma unroll
    for (int n = 0; n < 4; ++n)
      #pragma unroll
      for (int r = 0; r < 4; ++r) {
        int row = m0 + wr + m*16 + lg*4 + r;
        int col = n0 + wc + n*16 + lr;
        size_t idx = (size_t)row * N + col;
        float vv = acc[m][n][r];
        if (EPI == 0) {
          ((short*)Cv)[idx] = f2bf(vv);
        } else if (EPI == 1) {
          float gl = 0.5f * vv * (1.0f + erff(vv * 0.70710678118654752f));
          ((short*)Cv)[idx] = f2bf(gl);
        } else {
          ((float*)Cv)[idx] = vv + resid[idx];
        }
      }
}

__global__ __launch_bounds__(256) void attn_k(const short* __restrict__ Q,
                                              const short* __restrict__ K,
                                              const short* __restrict__ V,
                                              short* __restrict__ O) {
  const float scale = 0.08838834764831845f;
  const int qt = blockIdx.x;
  const int bh = blockIdx.y;
  const int b = bh >> 4, h = bh & 15;
  const size_t base = ((size_t)b * SEQ) * D_MODEL + (size_t)h * DK;
  const int t = threadIdx.x, wave = t >> 6, lane = t & 63, lr = lane & 15, lg = lane >> 4;

  __shared__ __align__(16) short Ks[32][136];
  __shared__ __align__(16) short Vt[128][40];
  __shared__ __align__(16) short Ps[4][32][40];

  const int qrow0 = qt * 128 + wave * 32;
  short8 qf[2][4];
  #pragma unroll
  for (int mq = 0; mq < 2; ++mq)
    #pragma unroll
    for (int ki = 0; ki < 4; ++ki)
      qf[mq][ki] = *(const short8*)(Q + base + (size_t)(qrow0 + mq*16 + lr) * D_MODEL + ki*32 + lg*8);

  f32x4 acc[2][8];
  const f32x4 z4 = {0.f, 0.f, 0.f, 0.f};
  #pragma unroll
  for (int mq = 0; mq < 2; ++mq)
    #pragma unroll
    for (int nd = 0; nd < 8; ++nd) acc[mq][nd] = z4;
  float mrow[2][4], lsum[2][4];
  #pragma unroll
  for (int mq = 0; mq < 2; ++mq)
    #pragma unroll
    for (int r = 0; r < 4; ++r) { mrow[mq][r] = -INFINITY; lsum[mq][r] = 0.f; }

  const int lastt = qt * 4 + 3;
  for (int tt = 0; tt <= lastt; ++tt) {
    #pragma unroll
    for (int i = 0; i < 2; ++i) {
      int u = t + 256*i; int r = u >> 4; int c = (u & 15) * 8;
      *(uint4*)&Ks[r][c] = *(const uint4*)(K + base + (size_t)(tt*32 + r) * D_MODEL + c);
      uint4 vv = *(const uint4*)(V + base + (size_t)(tt*32 + r) * D_MODEL + c);
      const short* sv = (const short*)&vv;
      #pragma unroll
      for (int j = 0; j < 8; ++j) Vt[c + j][r] = sv[j];
    }
    __syncthreads();
    if (tt <= qt * 4 + wave) {
      f32x4 sf[2][2] = {{z4, z4}, {z4, z4}};
      #pragma unroll
      for (int ki = 0; ki < 4; ++ki) {
        short8 kf0 = *(const short8*)&Ks[lr][ki*32 + lg*8];
        short8 kf1 = *(const short8*)&Ks[16 + lr][ki*32 + lg*8];
        sf[0][0] = MF(qf[0][ki], kf0, sf[0][0]);
        sf[0][1] = MF(qf[0][ki], kf1, sf[0][1]);
        sf[1][0] = MF(qf[1][ki], kf0, sf[1][0]);
        sf[1][1] = MF(qf[1][ki], kf1, sf[1][1]);
      }
      #pragma unroll
      for (int mq = 0; mq < 2; ++mq) {
        #pragma unroll
        for (int r = 0; r < 4; ++r) {
          int qg = qrow0 + mq*16 + lg*4 + r;
          float s0 = sf[mq][0][r] * scale;
          float s1 = sf[mq][1][r] * scale;
          if (tt*32 + lr > qg)       s0 = -INFINITY;
          if (tt*32 + 16 + lr > qg)  s1 = -INFINITY;
          float mx = fmaxf(s0, s1);
          mx = fmaxf(mx, __shfl_xor(mx, 1));
          mx = fmaxf(mx, __shfl_xor(mx, 2));
          mx = fmaxf(mx, __shfl_xor(mx, 4));
          mx = fmaxf(mx, __shfl_xor(mx, 8));
          float mnew = fmaxf(mrow[mq][r], mx);
          float alpha = __expf(mrow[mq][r] - mnew);
          mrow[mq][r] = mnew;
          float p0 = __expf(s0 - mnew);
          float p1 = __expf(s1 - mnew);
          float ps = p0 + p1;
          ps += __shfl_xor(ps, 1);
          ps += __shfl_xor(ps, 2);
          ps += __shfl_xor(ps, 4);
          ps += __shfl_xor(ps, 8);
          lsum[mq][r] = lsum[mq][r] * alpha + ps;
          #pragma unroll
          for (int nd = 0; nd < 8; ++nd) acc[mq][nd][r] *= alpha;
          Ps[wave][mq*16 + lg*4 + r][lr]      = f2bf(p0);
          Ps[wave][mq*16 + lg*4 + r][16 + lr] = f2bf(p1);
        }
      }
      asm volatile("s_waitcnt lgkmcnt(0)" ::: "memory");
      short8 pf0 = *(const short8*)&Ps[wave][lr][lg*8];
      short8 pf1 = *(const short8*)&Ps[wave][16 + lr][lg*8];
      #pragma unroll
      for (int nd = 0; nd < 8; ++nd) {
        short8 vf = *(const short8*)&Vt[nd*16 + lr][lg*8];
        acc[0][nd] = MF(pf0, vf, acc[0][nd]);
        acc[1][nd] = MF(pf1, vf, acc[1][nd]);
      }
    }
    __syncthreads();
  }

  #pragma unroll
  for (int mq = 0; mq < 2; ++mq)
    #pragma unroll
    for (int nd = 0; nd < 8; ++nd)
      #pragma unroll
      for (int r = 0; r < 4; ++r) {
        int row = qrow0 + mq*16 + lg*4 + r;
        O[base + (size_t)row * D_MODEL + nd*16 + lr] = f2bf(acc[mq][nd][r] / lsum[mq][r]);
      }
}

// ---------------- launch ----------------
extern "C" void kernel_launch(void* const* d_in, const int* in_sizes, int n_in,
                              void* d_out, int out_size, void* d_ws, size_t ws_size,
                              hipStream_t stream) {
  const float* x  = (const float*)d_in[0];
  const float* wq = (const float*)d_in[1];
  const float* wk = (const float*)d_in[2];
  const float* wv = (const float*)d_in[3];
  const float* wo = (const float*)d_in[4];
  const float* w1 = (const float*)d_in[5];
  const float* w2 = (const float*)d_in[6];
  const float* g1 = (const float*)d_in[7];
  const float* g2 = (const float*)d_in[8];
  float* out = (float*)d_out;
  char* ws = (char*)d_ws;

  const size_t NEED = (size_t)192 << 20;
  if (ws_size >= NEED) {
    // fast path layout (192 MiB):
    //   [0,24M) wqkv | [24,32M) wo | [32,64M) w1 | [64,96M) w2   (bf16 weights)
    //   [96,144M) qkv | [144,160M) vt | [160,176M) ab | [176,192M) xn
    //   oproj phase: partials (2x16M bf16) at [96,128)   (qkv/vt dead)
    //   FFN phase:   hb = [96,160M); FFN2 partials (2x16M bf16) at [160,192) (ab/xn dead)
    short* wqkv = (short*)(ws);
    short* wo_b = (short*)(ws + ((size_t)24 << 20));
    short* w1_b = (short*)(ws + ((size_t)32 << 20));
    short* w2_b = (short*)(ws + ((size_t)64 << 20));
    short* qkv  = (short*)(ws + ((size_t)96 << 20));
    short* vt   = (short*)(ws + ((size_t)144 << 20));
    short* ab   = (short*)(ws + ((size_t)160 << 20));
    short* xn   = (short*)(ws + ((size_t)176 << 20));
    short* hb   = (short*)(ws + ((size_t)96 << 20));
    short* po   = (short*)(ws + ((size_t)96 << 20));    // oproj partials (2x MROWSxD bf16)
    short* pf   = (short*)(ws + ((size_t)160 << 20));   // FFN2 partials (2x MROWSxD bf16)

    const int NW = D_MODEL * D_MODEL / 8;
    f2b_k<<<(NW + 255) / 256, 256, 0, stream>>>(wq, wqkv,                   NW);
    f2b_k<<<(NW + 255) / 256, 256, 0, stream>>>(wk, wqkv + (size_t)D_MODEL * D_MODEL,     NW);
    f2b_k<<<(NW + 255) / 256, 256, 0, stream>>>(wv, wqkv + (size_t)2 * D_MODEL * D_MODEL, NW);
    f2b_k<<<(NW + 255) / 256, 256, 0, stream>>>(wo, wo_b, NW);
    const int NF = DFF * D_MODEL / 8;
    f2b_k<<<(NF + 255) / 256, 256, 0, stream>>>(w1, w1_b, NF);
    f2b_k<<<(NF + 255) / 256, 256, 0, stream>>>(w2, w2_b, NF);

    const int N8 = MROWS * D_MODEL / 8;

    rmsnorm_k<<<MROWS, 256, 0, stream>>>(x, g1, xn);
    // QKV: 32x48 = 1536 blocks
    gemm128r<0,0><<<dim3(32 * 48), 256, 0, stream>>>(xn, wqkv, qkv, nullptr,
                                                     MROWS, 6144, D_MODEL, D_MODEL, 32);
    vtrans<<<dim3(SEQ/64, BATCH*NHEAD), 256, 0, stream>>>(qkv, vt);
    attn3<<<dim3(8, BATCH*NHEAD), 512, 0, stream>>>(qkv, vt, ab);
    // o-proj: split-K x2 -> 1024 blocks, bf16 partials; fused combine+resid+rmsnorm2
    gemm128r<0,1><<<dim3(32 * 16 * 2), 256, 0, stream>>>(ab, wo_b, po, nullptr,
                                                         MROWS, D_MODEL, D_MODEL / 2, D_MODEL, 32);
    combine_rms<<<MROWS, 256, 0, stream>>>(po, po + (size_t)MROWS * D_MODEL, x, g2, out, xn);
    // FFN1: 32x64 = 2048 blocks, GELU
    gemm128r<1,0><<<dim3(32 * 64), 256, 0, stream>>>(xn, w1_b, hb, nullptr,
                                                     MROWS, DFF, D_MODEL, D_MODEL, 32);
    // FFN2: split-K x2 -> 1024 blocks, bf16 partials; combine in-place with resid out
    gemm128r<0,1><<<dim3(32 * 16 * 2), 256, 0, stream>>>(hb, w2_b, pf, nullptr,
                                                         MROWS, D_MODEL, DFF / 2, DFF, 32);
    combine_bb<<<(N8 + 255) / 256, 256, 0, stream>>>(pf, pf + (size_t)MROWS * D_MODEL, out, out, N8);
  } else {
    // fallback: round-2 verified path (80 MiB)
    short* qb = (short*)(ws + ((size_t)0  << 20));
    short* kb = (short*)(ws + ((size_t)16 << 20));
    short* vb = (short*)(ws + ((size_t)32 << 20));
    short* ab = (short*)(ws + ((size_t)48 << 20));
    short* xn = (short*)(ws + ((size_t)64 << 20));
    short* hb = (short*)(ws + ((size_t)0  << 20));

    dim3 gproj(MROWS / 128, D_MODEL / 128);
    rmsnorm_k<<<MROWS, 256, 0, stream>>>(x, g1, xn);
    gemm_bt<0><<<gproj, 256, 0, stream>>>(xn, wq, qb, nullptr, MROWS, D_MODEL, D_MODEL);
    gemm_bt<0><<<gproj, 256, 0, stream>>>(xn, wk, kb, nullptr, MROWS, D_MODEL, D_MODEL);
    gemm_bt<0><<<gproj, 256, 0, stream>>>(xn, wv, vb, nullptr, MROWS, D_MODEL, D_MODEL);
    attn_k<<<dim3(SEQ / 128, BATCH * NHEAD), 256, 0, stream>>>(qb, kb, vb, ab);
    gemm_bt<2><<<gproj, 256, 0, stream>>>(ab, wo, out, x, MROWS, D_MODEL, D_MODEL);
    rmsnorm_k<<<MROWS, 256, 0, stream>>>(out, g2, xn);
    for (int half = 0; half < 2; ++half) {
      const short* xh = xn  + (size_t)half * 2048 * D_MODEL;
      float*       oh = out + (size_t)half * 2048 * D_MODEL;
      gemm_bt<1><<<dim3(2048 / 128, DFF / 128), 256, 0, stream>>>(xh, w1, hb, nullptr, 2048, DFF, D_MODEL);
      gemm_bt<2><<<dim3(2048 / 128, D_MODEL / 128), 256, 0, stream>>>(hb, w2, oh, oh, 2048, D_MODEL, DFF);
    }
  }
}

// Round 12
// 1135.501 us; speedup vs baseline: 3.0257x; 3.0257x over previous
//
#include <hip/hip_runtime.h>
#include <hip/hip_bf16.h>
#include <math.h>

// ---- problem constants ----
#define D_MODEL 2048
#define SEQ     2048
#define BATCH   2
#define NHEAD   16
#define DK      128
#define DFF     8192
#define MROWS   (BATCH*SEQ)   // 4096 rows

typedef short short8 __attribute__((ext_vector_type(8)));   // 8 bf16 in 4 VGPRs
typedef float f32x4  __attribute__((ext_vector_type(4)));

__device__ __forceinline__ short f2bf(float f) {
  union { __hip_bfloat16 b; short s; } u;
  u.b = __float2bfloat16(f);
  return u.s;
}
__device__ __forceinline__ float bf2f(short s) {
  union { unsigned u; float f; } u;
  u.u = ((unsigned)(unsigned short)s) << 16;
  return u.f;
}

#define MF(a, b, c) __builtin_amdgcn_mfma_f32_16x16x32_bf16(a, b, c, 0, 0, 0)

__device__ __forceinline__ void gload_lds16(const void* g, void* l) {
  __builtin_amdgcn_global_load_lds(
      (const __attribute__((address_space(1))) unsigned int*)g,
      (__attribute__((address_space(3))) unsigned int*)l, 16, 0, 0);
}

// ---------------- RMSNorm: fp32 in -> bf16 out ----------------
__global__ __launch_bounds__(256) void rmsnorm_k(const float* __restrict__ x,
                                                 const float* __restrict__ g,
                                                 short* __restrict__ o) {
  const int row = blockIdx.x;
  const int t = threadIdx.x;
  const float4* xr = (const float4*)(x + (size_t)row * D_MODEL);
  const float4* gr = (const float4*)g;
  float4 v0 = xr[2*t], v1 = xr[2*t+1];
  float s = v0.x*v0.x + v0.y*v0.y + v0.z*v0.z + v0.w*v0.w
          + v1.x*v1.x + v1.y*v1.y + v1.z*v1.z + v1.w*v1.w;
  #pragma unroll
  for (int off = 1; off < 64; off <<= 1) s += __shfl_xor(s, off);
  __shared__ float red[4];
  if ((t & 63) == 0) red[t >> 6] = s;
  __syncthreads();
  float tot = red[0] + red[1] + red[2] + red[3];
  float inv = rsqrtf(tot * (1.0f / D_MODEL) + 1e-5f);
  float4 g0 = gr[2*t], g1v = gr[2*t+1];
  short8 ov;
  ov[0] = f2bf(v0.x * inv * g0.x);
  ov[1] = f2bf(v0.y * inv * g0.y);
  ov[2] = f2bf(v0.z * inv * g0.z);
  ov[3] = f2bf(v0.w * inv * g0.w);
  ov[4] = f2bf(v1.x * inv * g1v.x);
  ov[5] = f2bf(v1.y * inv * g1v.y);
  ov[6] = f2bf(v1.z * inv * g1v.z);
  ov[7] = f2bf(v1.w * inv * g1v.w);
  *((short8*)(o + (size_t)row * D_MODEL) + t) = ov;
}

// ---------------- fp32 -> bf16 convert (weights, one-time) ----------------
__global__ __launch_bounds__(256) void f2b_k(const float* __restrict__ src,
                                             short* __restrict__ dst, int n8) {
  int i = blockIdx.x * 256 + threadIdx.x;
  if (i >= n8) return;
  const float4* s4 = (const float4*)src + 2 * (size_t)i;
  float4 a = s4[0], b = s4[1];
  short8 o = { f2bf(a.x), f2bf(a.y), f2bf(a.z), f2bf(a.w),
               f2bf(b.x), f2bf(b.y), f2bf(b.z), f2bf(b.w) };
  *((short8*)dst + i) = o;
}

// ---------------- split-K combine: o = bf16(p0) + bf16(p1) + fp32(r) ----------------
__global__ __launch_bounds__(256) void combine_bb(const short* __restrict__ p0,
                                                  const short* __restrict__ p1,
                                                  const float* __restrict__ r,
                                                  float* __restrict__ o, int n8) {
  int i = blockIdx.x * 256 + threadIdx.x;
  if (i >= n8) return;
  short8 a = ((const short8*)p0)[i];
  short8 b = ((const short8*)p1)[i];
  float4 r0 = ((const float4*)r)[2 * (size_t)i];
  float4 r1 = ((const float4*)r)[2 * (size_t)i + 1];
  float4 o0, o1;
  o0.x = bf2f(a[0]) + bf2f(b[0]) + r0.x;
  o0.y = bf2f(a[1]) + bf2f(b[1]) + r0.y;
  o0.z = bf2f(a[2]) + bf2f(b[2]) + r0.z;
  o0.w = bf2f(a[3]) + bf2f(b[3]) + r0.w;
  o1.x = bf2f(a[4]) + bf2f(b[4]) + r1.x;
  o1.y = bf2f(a[5]) + bf2f(b[5]) + r1.y;
  o1.z = bf2f(a[6]) + bf2f(b[6]) + r1.z;
  o1.w = bf2f(a[7]) + bf2f(b[7]) + r1.w;
  ((float4*)o)[2 * (size_t)i]     = o0;
  ((float4*)o)[2 * (size_t)i + 1] = o1;
}

// ---- fused: x2 = bf16(p0)+bf16(p1)+x (fp32, ->out) ; xn = rmsnorm(x2, g) bf16 ----
__global__ __launch_bounds__(256) void combine_rms(const short* __restrict__ p0,
                                                   const short* __restrict__ p1,
                                                   const float* __restrict__ xres,
                                                   const float* __restrict__ g,
                                                   float* __restrict__ out,
                                                   short* __restrict__ xn) {
  const int row = blockIdx.x;
  const int t = threadIdx.x;
  const size_t b8 = (size_t)row * (D_MODEL / 8) + t;
  short8 a = ((const short8*)p0)[b8];
  short8 b = ((const short8*)p1)[b8];
  float4 r0 = ((const float4*)xres)[2 * b8];
  float4 r1 = ((const float4*)xres)[2 * b8 + 1];
  float v[8];
  v[0] = bf2f(a[0]) + bf2f(b[0]) + r0.x;
  v[1] = bf2f(a[1]) + bf2f(b[1]) + r0.y;
  v[2] = bf2f(a[2]) + bf2f(b[2]) + r0.z;
  v[3] = bf2f(a[3]) + bf2f(b[3]) + r0.w;
  v[4] = bf2f(a[4]) + bf2f(b[4]) + r1.x;
  v[5] = bf2f(a[5]) + bf2f(b[5]) + r1.y;
  v[6] = bf2f(a[6]) + bf2f(b[6]) + r1.z;
  v[7] = bf2f(a[7]) + bf2f(b[7]) + r1.w;
  float4 o0 = {v[0], v[1], v[2], v[3]}, o1 = {v[4], v[5], v[6], v[7]};
  ((float4*)out)[2 * b8]     = o0;
  ((float4*)out)[2 * b8 + 1] = o1;
  float s = 0.f;
  #pragma unroll
  for (int j = 0; j < 8; ++j) s += v[j] * v[j];
  #pragma unroll
  for (int off = 1; off < 64; off <<= 1) s += __shfl_xor(s, off);
  __shared__ float red[4];
  if ((t & 63) == 0) red[t >> 6] = s;
  __syncthreads();
  float tot = red[0] + red[1] + red[2] + red[3];
  float inv = rsqrtf(tot * (1.0f / D_MODEL) + 1e-5f);
  float4 g0 = ((const float4*)g)[2 * t], g1v = ((const float4*)g)[2 * t + 1];
  short8 ov;
  ov[0] = f2bf(v[0] * inv * g0.x);
  ov[1] = f2bf(v[1] * inv * g0.y);
  ov[2] = f2bf(v[2] * inv * g0.z);
  ov[3] = f2bf(v[3] * inv * g0.w);
  ov[4] = f2bf(v[4] * inv * g1v.x);
  ov[5] = f2bf(v[5] * inv * g1v.y);
  ov[6] = f2bf(v[6] * inv * g1v.z);
  ov[7] = f2bf(v[7] * inv * g1v.w);
  ((short8*)xn)[b8] = ov;
}

// ======== 256x128 single-buffer GEMM, 128x64 WAVE tile, 3 blocks/CU ========
// C[M,N] = A[M,K](bf16) * B[N,K](bf16)^T. 256 thr = 4 waves (2M x 2N), wave 128x64
// (acc[8][4]: A-frag reuse across 4 B-frags -> LDS reads/MFMA drop 0.5->0.375 KB,
// raising the LDS-BW MfmaUtil cap ~40%->~55%). LDS = 48 KB single buffer ->
// launch_bounds(256,3) = 3 blocks/CU: independent barrier domains cover the
// per-tile drain (R10-verified). m97-exact control flow with builtin
// global_load_lds (compiler inserts correct waits). XOR swizzle both sides
// -> 0 bank conflicts (R10-verified). EPI: 0 bf16; 1 GELU bf16; 2 +resid fp32.
// SPLIT: split-K x2, bf16 partials at Cv + ks*M*N.
template<int EPI, int SPLIT>
__global__ __launch_bounds__(256, 3) void gemm256x128(const short* __restrict__ A,
                                                      const short* __restrict__ Bp,
                                                      void* Cv,
                                                      const float* __restrict__ resid,
                                                      int M, int N, int Kloop,
                                                      int lda, int nbx) {
  __shared__ __align__(16) short As[256 * 64];   // 32 KB
  __shared__ __align__(16) short Bs[128 * 64];   // 16 KB
  const int nk = Kloop >> 6;
  const int cpx = gridDim.x >> 3;                // grid % 8 == 0 (bijective XCD swizzle)
  const int lin = (blockIdx.x & 7) * cpx + (blockIdx.x >> 3);
  const int bx = lin % nbx;
  int row2 = lin / nbx, by, ks = 0;
  if (SPLIT) { ks = row2 & 1; by = row2 >> 1; } else { by = row2; }
  const int m0 = bx * 256, n0 = by * 128;
  if (SPLIT) { A += (size_t)ks * Kloop; Bp += (size_t)ks * Kloop; }

  const int t = threadIdx.x, w = t >> 6, lane = t & 63, lr = lane & 15, lg = lane >> 4;
  const int wm = w >> 1, wn = w & 1;             // wave tile: rows wm*128..+128, cols wn*64..+64

  // staging: thread t -> rows r+32i, 16B chunk c8; source col pre-swizzled
  const int r = t >> 3, c8 = t & 7;
  const int swc = (c8 ^ (r & 7)) << 3;           // (r+32i)&7 == r&7
  const short* pA = A  + (size_t)(m0 + r) * lda + swc;
  const short* pB = Bp + (size_t)(n0 + r) * lda + swc;
  const size_t l32 = (size_t)32 * lda;

  f32x4 acc[8][4];
  const f32x4 z4 = {0.f, 0.f, 0.f, 0.f};
  #pragma unroll
  for (int m = 0; m < 8; ++m)
    #pragma unroll
    for (int n = 0; n < 4; ++n) acc[m][n] = z4;

  const int rsw = (lr & 7) << 3;                 // lane-constant read swizzle (shorts)

  for (int T = 0; T < nk; ++T) {
    // ---- stage tile T: A 8 chunks (256 rows), B 4 chunks (128 rows) ----
    #pragma unroll
    for (int i = 0; i < 8; ++i)
      gload_lds16(pA + (size_t)T * 64 + i * l32, &As[i * 2048 + w * 512]);
    #pragma unroll
    for (int i = 0; i < 4; ++i)
      gload_lds16(pB + (size_t)T * 64 + i * l32, &Bs[i * 2048 + w * 512]);
    __syncthreads();

    // ---- compute tile T: per k-half, 8 A-frags reused over 4 B-frags ----
    #pragma unroll
    for (int kk = 0; kk < 2; ++kk) {
      short8 af[8];
      #pragma unroll
      for (int m = 0; m < 8; ++m) {
        int ar = wm * 128 + m * 16 + lr;
        af[m] = *(const short8*)&As[ar * 64 + ((kk * 32 + lg * 8) ^ rsw)];
      }
      #pragma unroll
      for (int n = 0; n < 4; ++n) {
        int br = wn * 64 + n * 16 + lr;
        short8 bf = *(const short8*)&Bs[br * 64 + ((kk * 32 + lg * 8) ^ rsw)];
        #pragma unroll
        for (int m = 0; m < 8; ++m) acc[m][n] = MF(af[m], bf, acc[m][n]);
      }
    }
    if (T + 1 < nk) __syncthreads();   // reads done before next stage overwrites
  }

  // ---- epilogue ----
  short* Cs = (short*)Cv;
  if (SPLIT) Cs += (size_t)ks * ((size_t)M * N);
  #pragma unroll
  for (int m = 0; m < 8; ++m)
    #pragma unroll
    for (int n = 0; n < 4; ++n)
      #pragma unroll
      for (int rr = 0; rr < 4; ++rr) {
        int row = m0 + wm * 128 + m * 16 + lg * 4 + rr;
        int col = n0 + wn * 64 + n * 16 + lr;
        size_t idx = (size_t)row * N + col;
        float vv = acc[m][n][rr];
        if (EPI == 0) {
          Cs[idx] = f2bf(vv);
        } else if (EPI == 1) {
          float gl = 0.5f * vv * (1.0f + erff(vv * 0.70710678118654752f));
          ((short*)Cv)[idx] = f2bf(gl);
        } else {
          ((float*)Cv)[idx] = vv + resid[idx];
        }
      }
}

// ---------------- V transpose: qkv[.., v cols] -> vt[b][h][d][s] ----------------
__global__ __launch_bounds__(256) void vtrans(const short* __restrict__ QKV,
                                              short* __restrict__ VT) {
  const int st = blockIdx.x;   // s tile of 64
  const int bh = blockIdx.y;
  const int b = bh >> 4, h = bh & 15;
  const int t = threadIdx.x;
  __shared__ __align__(16) short T[64 * 128];
  const short* Vsrc = QKV + ((size_t)b * SEQ) * 6144 + 2 * D_MODEL + h * DK;
  {
    int r = t >> 4, c = (t & 15) * 8;
    #pragma unroll
    for (int i = 0; i < 4; ++i) {
      int rr = r + 16 * i;
      uint4 vv = *(const uint4*)(Vsrc + (size_t)(st * 64 + rr) * 6144 + c);
      *(uint4*)&T[rr * 128 + (c ^ (((rr >> 3) & 7) << 3))] = vv;
    }
  }
  __syncthreads();
  short* dst = VT + ((size_t)bh * DK) * SEQ + st * 64;
  {
    int c2 = (t & 7) * 8;
    #pragma unroll
    for (int i = 0; i < 4; ++i) {
      int d = (t >> 3) + 32 * i;
      short8 ov;
      #pragma unroll
      for (int j = 0; j < 8; ++j)
        ov[j] = T[(c2 + j) * 128 + (d ^ ((((c2 + j) >> 3) & 7) << 3))];
      *(short8*)(dst + (size_t)d * SEQ + c2) = ov;
    }
  }
}

// ---------------- Flash attention v3 (round-4 verified) ----------------
__global__ __launch_bounds__(512, 2) void attn3(const short* __restrict__ QKV,
                                                const short* __restrict__ VT,
                                                short* __restrict__ O) {
  const float SC = 0.12751743f;   // (1/sqrt(128)) * log2(e)
  const int a = blockIdx.x, bh = blockIdx.y;
  const int b = bh >> 4, h = bh & 15;
  const int t = threadIdx.x, w = t >> 6, lane = t & 63, lr = lane & 15, lg = lane >> 4;
  const short* Qp = QKV + ((size_t)b * SEQ) * 6144 + h * DK;
  const short* Kp = Qp + D_MODEL;
  const short* Vp = VT + ((size_t)bh * DK) * SEQ;   // [d][s]
  __shared__ __align__(16) short Ks[2][64 * 128];
  __shared__ __align__(16) short Vs[2][128 * 64];
  __shared__ __align__(16) short Ps[8][16][72];

  const int krr = t >> 4, kcc = (t & 15) * 8;
  const int vdd = t >> 3, vcc = (t & 7) * 8;
  const f32x4 z4 = {0.f, 0.f, 0.f, 0.f};

  for (int sub = 0; sub < 2; ++sub) {
    const int ts = sub ? (15 - a) : a;
    const int nt = 2 * ts + 2;
    const int qrow0 = ts * 128 + w * 16;

    short8 qf[4];
    #pragma unroll
    for (int ki = 0; ki < 4; ++ki)
      qf[ki] = *(const short8*)(Qp + (size_t)(qrow0 + lr) * 6144 + ki * 32 + lg * 8);

    f32x4 acc[8];
    #pragma unroll
    for (int nd = 0; nd < 8; ++nd) acc[nd] = z4;
    float mrow[4], lsum[4];
    #pragma unroll
    for (int r = 0; r < 4; ++r) { mrow[r] = -INFINITY; lsum[r] = 0.f; }

    uint4 krg[2], vrg[2];
    #pragma unroll
    for (int i = 0; i < 2; ++i) {
      krg[i] = *(const uint4*)(Kp + (size_t)(krr + 32 * i) * 6144 + kcc);
      vrg[i] = *(const uint4*)(Vp + (size_t)(vdd + 64 * i) * SEQ + vcc);
    }
    __syncthreads();
    #pragma unroll
    for (int i = 0; i < 2; ++i) {
      int r = krr + 32 * i;
      *(uint4*)&Ks[0][(r * 128 + kcc) ^ ((r & 7) << 3)] = krg[i];
      int d = vdd + 64 * i;
      *(uint4*)&Vs[0][(d * 64 + vcc) ^ ((d & 7) << 3)] = vrg[i];
    }
    __syncthreads();

    int cur = 0;
    for (int tt = 0; tt < nt; ++tt) {
      const bool pre = (tt + 1 < nt);
      if (pre) {
        #pragma unroll
        for (int i = 0; i < 2; ++i) {
          krg[i] = *(const uint4*)(Kp + (size_t)((tt + 1) * 64 + krr + 32 * i) * 6144 + kcc);
          vrg[i] = *(const uint4*)(Vp + (size_t)(vdd + 64 * i) * SEQ + (tt + 1) * 64 + vcc);
        }
      }

      f32x4 sf[4] = {z4, z4, z4, z4};
      #pragma unroll
      for (int ki = 0; ki < 4; ++ki) {
        #pragma unroll
        for (int nk = 0; nk < 4; ++nk) {
          int rr = nk * 16 + lr;
          short8 kf = *(const short8*)&Ks[cur][(rr * 128 + ki * 32 + lg * 8) ^ ((rr & 7) << 3)];
          sf[nk] = MF(qf[ki], kf, sf[nk]);
        }
      }

      const bool diag = (tt * 64 + 63 > qrow0);
      #pragma unroll
      for (int r = 0; r < 4; ++r) {
        int qg = qrow0 + lg * 4 + r;
        float s0 = sf[0][r] * SC, s1 = sf[1][r] * SC, s2 = sf[2][r] * SC, s3 = sf[3][r] * SC;
        if (diag) {
          int c0 = tt * 64 + lr;
          s0 = (c0      <= qg) ? s0 : -3.0e38f;
          s1 = (c0 + 16 <= qg) ? s1 : -3.0e38f;
          s2 = (c0 + 32 <= qg) ? s2 : -3.0e38f;
          s3 = (c0 + 48 <= qg) ? s3 : -3.0e38f;
        }
        float mx = fmaxf(fmaxf(s0, s1), fmaxf(s2, s3));
        mx = fmaxf(mx, __shfl_xor(mx, 1));
        mx = fmaxf(mx, __shfl_xor(mx, 2));
        mx = fmaxf(mx, __shfl_xor(mx, 4));
        mx = fmaxf(mx, __shfl_xor(mx, 8));
        float mnew = fmaxf(mrow[r], mx);
        float alpha = exp2f(mrow[r] - mnew);
        mrow[r] = mnew;
        float p0 = exp2f(s0 - mnew), p1 = exp2f(s1 - mnew),
              p2 = exp2f(s2 - mnew), p3 = exp2f(s3 - mnew);
        lsum[r] = lsum[r] * alpha + ((p0 + p1) + (p2 + p3));
        #pragma unroll
        for (int nd = 0; nd < 8; ++nd) acc[nd][r] *= alpha;
        short* pr = &Ps[w][lg * 4 + r][0];
        pr[lr]      = f2bf(p0);
        pr[16 + lr] = f2bf(p1);
        pr[32 + lr] = f2bf(p2);
        pr[48 + lr] = f2bf(p3);
      }
      asm volatile("s_waitcnt lgkmcnt(0)" ::: "memory");
      __builtin_amdgcn_sched_barrier(0);

      short8 pf0 = *(const short8*)&Ps[w][lr][lg * 8];
      short8 pf1 = *(const short8*)&Ps[w][lr][32 + lg * 8];
      #pragma unroll
      for (int nd = 0; nd < 8; ++nd) {
        int rr = nd * 16 + lr;
        short8 vf0 = *(const short8*)&Vs[cur][(rr * 64 + lg * 8) ^ ((rr & 7) << 3)];
        short8 vf1 = *(const short8*)&Vs[cur][(rr * 64 + 32 + lg * 8) ^ ((rr & 7) << 3)];
        acc[nd] = MF(pf0, vf0, acc[nd]);
        acc[nd] = MF(pf1, vf1, acc[nd]);
      }
      __syncthreads();
      if (pre) {
        #pragma unroll
        for (int i = 0; i < 2; ++i) {
          int r = krr + 32 * i;
          *(uint4*)&Ks[cur ^ 1][(r * 128 + kcc) ^ ((r & 7) << 3)] = krg[i];
          int d = vdd + 64 * i;
          *(uint4*)&Vs[cur ^ 1][(d * 64 + vcc) ^ ((d & 7) << 3)] = vrg[i];
        }
      }
      __syncthreads();
      cur ^= 1;
    }

    float inv[4];
    #pragma unroll
    for (int r = 0; r < 4; ++r) {
      float ls = lsum[r];
      ls += __shfl_xor(ls, 1);
      ls += __shfl_xor(ls, 2);
      ls += __shfl_xor(ls, 4);
      ls += __shfl_xor(ls, 8);
      inv[r] = 1.0f / ls;
    }
    #pragma unroll
    for (int nd = 0; nd < 8; ++nd)
      #pragma unroll
      for (int r = 0; r < 4; ++r) {
        int row = qrow0 + lg * 4 + r;
        O[(size_t)(b * SEQ + row) * D_MODEL + h * DK + nd * 16 + lr] = f2bf(acc[nd][r] * inv[r]);
      }
  }
}

// ======== FALLBACK PATH (round-2 verified kernels) ========
template<int EPI>
__global__ __launch_bounds__(256) void gemm_bt(const short* __restrict__ A,
                                               const float* __restrict__ B,
                                               void* Cv,
                                               const float* resid,
                                               int M, int N, int K) {
  __shared__ __align__(16) short As[128][72];
  __shared__ __align__(16) short Bs[128][72];
  const int t = threadIdx.x;
  const int m0 = blockIdx.x * 128, n0 = blockIdx.y * 128;
  const int wave = t >> 6, lane = t & 63, lr = lane & 15, lg = lane >> 4;
  const int wr = (wave >> 1) * 64, wc = (wave & 1) * 64;

  f32x4 acc[4][4];
  const f32x4 z4 = {0.f, 0.f, 0.f, 0.f};
  #pragma unroll
  for (int m = 0; m < 4; ++m)
    #pragma unroll
    for (int n = 0; n < 4; ++n) acc[m][n] = z4;

  int ar[4], ac[4];
  #pragma unroll
  for (int i = 0; i < 4; ++i) { int u = t + 256*i; ar[i] = u >> 3; ac[i] = (u & 7) * 8; }

  for (int k0 = 0; k0 < K; k0 += 64) {
    #pragma unroll
    for (int i = 0; i < 4; ++i) {
      uint4 va = *(const uint4*)(A + (size_t)(m0 + ar[i]) * K + k0 + ac[i]);
      *(uint4*)&As[ar[i]][ac[i]] = va;
    }
    #pragma unroll
    for (int i = 0; i < 4; ++i) {
      const float4* bp = (const float4*)(B + (size_t)(n0 + ar[i]) * K + k0 + ac[i]);
      float4 b0 = bp[0], b1 = bp[1];
      short8 pb = { f2bf(b0.x), f2bf(b0.y), f2bf(b0.z), f2bf(b0.w),
                    f2bf(b1.x), f2bf(b1.y), f2bf(b1.z), f2bf(b1.w) };
      *(short8*)&Bs[ar[i]][ac[i]] = pb;
    }
    __syncthreads();
    #pragma unroll
    for (int kk = 0; kk < 64; kk += 32) {
      short8 af[4], bfr[4];
      #pragma unroll
      for (int m = 0; m < 4; ++m) af[m]  = *(const short8*)&As[wr + m*16 + lr][kk + lg*8];
      #pragma unroll
      for (int n = 0; n < 4; ++n) bfr[n] = *(const short8*)&Bs[wc + n*16 + lr][kk + lg*8];
      #pragma unroll
      for (int m = 0; m < 4; ++m)
        #pragma unroll
        for (int n = 0; n < 4; ++n)
          acc[m][n] = MF(af[m], bfr[n], acc[m][n]);
    }
    __syncthreads();
  }

  #pragma unroll
  for (int m = 0; m < 4; ++m)
    #pragma unroll
    for (int n = 0; n < 4; ++n)
      #pragma unroll
      for (int r = 0; r < 4; ++r) {
        int row = m0 + wr + m*16 + lg*4 + r;
        int col = n0 + wc + n*16 + lr;
        size_t idx = (size_t)row * N + col;
        float vv = acc[m][n][r];
        if (EPI == 0) {
          ((short*)Cv)[idx] = f2bf(vv);
        } else if (EPI == 1) {
          float gl = 0.5f * vv * (1.0f + erff(vv * 0.70710678118654752f));
          ((short*)Cv)[idx] = f2bf(gl);
        } else {
          ((float*)Cv)[idx] = vv + resid[idx];
        }
      }
}

__global__ __launch_bounds__(256) void attn_k(const short* __restrict__ Q,
                                              const short* __restrict__ K,
                                              const short* __restrict__ V,
                                              short* __restrict__ O) {
  const float scale = 0.08838834764831845f;
  const int qt = blockIdx.x;
  const int bh = blockIdx.y;
  const int b = bh >> 4, h = bh & 15;
  const size_t base = ((size_t)b * SEQ) * D_MODEL + (size_t)h * DK;
  const int t = threadIdx.x, wave = t >> 6, lane = t & 63, lr = lane & 15, lg = lane >> 4;

  __shared__ __align__(16) short Ks[32][136];
  __shared__ __align__(16) short Vt[128][40];
  __shared__ __align__(16) short Ps[4][32][40];

  const int qrow0 = qt * 128 + wave * 32;
  short8 qf[2][4];
  #pragma unroll
  for (int mq = 0; mq < 2; ++mq)
    #pragma unroll
    for (int ki = 0; ki < 4; ++ki)
      qf[mq][ki] = *(const short8*)(Q + base + (size_t)(qrow0 + mq*16 + lr) * D_MODEL + ki*32 + lg*8);

  f32x4 acc[2][8];
  const f32x4 z4 = {0.f, 0.f, 0.f, 0.f};
  #pragma unroll
  for (int mq = 0; mq < 2; ++mq)
    #pragma unroll
    for (int nd = 0; nd < 8; ++nd) acc[mq][nd] = z4;
  float mrow[2][4], lsum[2][4];
  #pragma unroll
  for (int mq = 0; mq < 2; ++mq)
    #pragma unroll
    for (int r = 0; r < 4; ++r) { mrow[mq][r] = -INFINITY; lsum[mq][r] = 0.f; }

  const int lastt = qt * 4 + 3;
  for (int tt = 0; tt <= lastt; ++tt) {
    #pragma unroll
    for (int i = 0; i < 2; ++i) {
      int u = t + 256*i; int r = u >> 4; int c = (u & 15) * 8;
      *(uint4*)&Ks[r][c] = *(const uint4*)(K + base + (size_t)(tt*32 + r) * D_MODEL + c);
      uint4 vv = *(const uint4*)(V + base + (size_t)(tt*32 + r) * D_MODEL + c);
      const short* sv = (const short*)&vv;
      #pragma unroll
      for (int j = 0; j < 8; ++j) Vt[c + j][r] = sv[j];
    }
    __syncthreads();
    if (tt <= qt * 4 + wave) {
      f32x4 sf[2][2] = {{z4, z4}, {z4, z4}};
      #pragma unroll
      for (int ki = 0; ki < 4; ++ki) {
        short8 kf0 = *(const short8*)&Ks[lr][ki*32 + lg*8];
        short8 kf1 = *(const short8*)&Ks[16 + lr][ki*32 + lg*8];
        sf[0][0] = MF(qf[0][ki], kf0, sf[0][0]);
        sf[0][1] = MF(qf[0][ki], kf1, sf[0][1]);
        sf[1][0] = MF(qf[1][ki], kf0, sf[1][0]);
        sf[1][1] = MF(qf[1][ki], kf1, sf[1][1]);
      }
      #pragma unroll
      for (int mq = 0; mq < 2; ++mq) {
        #pragma unroll
        for (int r = 0; r < 4; ++r) {
          int qg = qrow0 + mq*16 + lg*4 + r;
          float s0 = sf[mq][0][r] * scale;
          float s1 = sf[mq][1][r] * scale;
          if (tt*32 + lr > qg)       s0 = -INFINITY;
          if (tt*32 + 16 + lr > qg)  s1 = -INFINITY;
          float mx = fmaxf(s0, s1);
          mx = fmaxf(mx, __shfl_xor(mx, 1));
          mx = fmaxf(mx, __shfl_xor(mx, 2));
          mx = fmaxf(mx, __shfl_xor(mx, 4));
          mx = fmaxf(mx, __shfl_xor(mx, 8));
          float mnew = fmaxf(mrow[mq][r], mx);
          float alpha = __expf(mrow[mq][r] - mnew);
          mrow[mq][r] = mnew;
          float p0 = __expf(s0 - mnew);
          float p1 = __expf(s1 - mnew);
          float ps = p0 + p1;
          ps += __shfl_xor(ps, 1);
          ps += __shfl_xor(ps, 2);
          ps += __shfl_xor(ps, 4);
          ps += __shfl_xor(ps, 8);
          lsum[mq][r] = lsum[mq][r] * alpha + ps;
          #pragma unroll
          for (int nd = 0; nd < 8; ++nd) acc[mq][nd][r] *= alpha;
          Ps[wave][mq*16 + lg*4 + r][lr]      = f2bf(p0);
          Ps[wave][mq*16 + lg*4 + r][16 + lr] = f2bf(p1);
        }
      }
      asm volatile("s_waitcnt lgkmcnt(0)" ::: "memory");
      short8 pf0 = *(const short8*)&Ps[wave][lr][lg*8];
      short8 pf1 = *(const short8*)&Ps[wave][16 + lr][lg*8];
      #pragma unroll
      for (int nd = 0; nd < 8; ++nd) {
        short8 vf = *(const short8*)&Vt[nd*16 + lr][lg*8];
        acc[0][nd] = MF(pf0, vf, acc[0][nd]);
        acc[1][nd] = MF(pf1, vf, acc[1][nd]);
      }
    }
    __syncthreads();
  }

  #pragma unroll
  for (int mq = 0; mq < 2; ++mq)
    #pragma unroll
    for (int nd = 0; nd < 8; ++nd)
      #pragma unroll
      for (int r = 0; r < 4; ++r) {
        int row = qrow0 + mq*16 + lg*4 + r;
        O[base + (size_t)row * D_MODEL + nd*16 + lr] = f2bf(acc[mq][nd][r] / lsum[mq][r]);
      }
}

// ---------------- launch ----------------
extern "C" void kernel_launch(void* const* d_in, const int* in_sizes, int n_in,
                              void* d_out, int out_size, void* d_ws, size_t ws_size,
                              hipStream_t stream) {
  const float* x  = (const float*)d_in[0];
  const float* wq = (const float*)d_in[1];
  const float* wk = (const float*)d_in[2];
  const float* wv = (const float*)d_in[3];
  const float* wo = (const float*)d_in[4];
  const float* w1 = (const float*)d_in[5];
  const float* w2 = (const float*)d_in[6];
  const float* g1 = (const float*)d_in[7];
  const float* g2 = (const float*)d_in[8];
  float* out = (float*)d_out;
  char* ws = (char*)d_ws;

  const size_t NEED = (size_t)192 << 20;
  if (ws_size >= NEED) {
    // fast path layout (192 MiB):
    //   [0,24M) wqkv | [24,32M) wo | [32,64M) w1 | [64,96M) w2   (bf16 weights)
    //   [96,144M) qkv | [144,160M) vt | [160,176M) ab | [176,192M) xn
    //   oproj phase: partials (2x16M bf16) at [96,128)   (qkv/vt dead)
    //   FFN phase:   hb = [96,160M); FFN2 partials (2x16M bf16) at [160,192) (ab/xn dead)
    short* wqkv = (short*)(ws);
    short* wo_b = (short*)(ws + ((size_t)24 << 20));
    short* w1_b = (short*)(ws + ((size_t)32 << 20));
    short* w2_b = (short*)(ws + ((size_t)64 << 20));
    short* qkv  = (short*)(ws + ((size_t)96 << 20));
    short* vt   = (short*)(ws + ((size_t)144 << 20));
    short* ab   = (short*)(ws + ((size_t)160 << 20));
    short* xn   = (short*)(ws + ((size_t)176 << 20));
    short* hb   = (short*)(ws + ((size_t)96 << 20));
    short* po   = (short*)(ws + ((size_t)96 << 20));    // oproj partials (2x MROWSxD bf16)
    short* pf   = (short*)(ws + ((size_t)160 << 20));   // FFN2 partials (2x MROWSxD bf16)

    const int NW = D_MODEL * D_MODEL / 8;
    f2b_k<<<(NW + 255) / 256, 256, 0, stream>>>(wq, wqkv,                   NW);
    f2b_k<<<(NW + 255) / 256, 256, 0, stream>>>(wk, wqkv + (size_t)D_MODEL * D_MODEL,     NW);
    f2b_k<<<(NW + 255) / 256, 256, 0, stream>>>(wv, wqkv + (size_t)2 * D_MODEL * D_MODEL, NW);
    f2b_k<<<(NW + 255) / 256, 256, 0, stream>>>(wo, wo_b, NW);
    const int NF = DFF * D_MODEL / 8;
    f2b_k<<<(NF + 255) / 256, 256, 0, stream>>>(w1, w1_b, NF);
    f2b_k<<<(NF + 255) / 256, 256, 0, stream>>>(w2, w2_b, NF);

    const int N8 = MROWS * D_MODEL / 8;

    rmsnorm_k<<<MROWS, 256, 0, stream>>>(x, g1, xn);
    // QKV: (4096/256)x(6144/128) = 16x48 = 768 blocks (3/CU)
    gemm256x128<0,0><<<dim3(16 * 48), 256, 0, stream>>>(xn, wqkv, qkv, nullptr,
                                                        MROWS, 6144, D_MODEL, D_MODEL, 16);
    vtrans<<<dim3(SEQ/64, BATCH*NHEAD), 256, 0, stream>>>(qkv, vt);
    attn3<<<dim3(8, BATCH*NHEAD), 512, 0, stream>>>(qkv, vt, ab);
    // o-proj: split-K x2 -> 16x16x2 = 512 blocks, bf16 partials; fused combine+resid+rmsnorm2
    gemm256x128<0,1><<<dim3(16 * 16 * 2), 256, 0, stream>>>(ab, wo_b, po, nullptr,
                                                            MROWS, D_MODEL, D_MODEL / 2, D_MODEL, 16);
    combine_rms<<<MROWS, 256, 0, stream>>>(po, po + (size_t)MROWS * D_MODEL, x, g2, out, xn);
    // FFN1: 16x64 = 1024 blocks, GELU
    gemm256x128<1,0><<<dim3(16 * 64), 256, 0, stream>>>(xn, w1_b, hb, nullptr,
                                                        MROWS, DFF, D_MODEL, D_MODEL, 16);
    // FFN2: split-K x2 -> 512 blocks, bf16 partials; combine in-place with resid out
    gemm256x128<0,1><<<dim3(16 * 16 * 2), 256, 0, stream>>>(hb, w2_b, pf, nullptr,
                                                            MROWS, D_MODEL, DFF / 2, DFF, 16);
    combine_bb<<<(N8 + 255) / 256, 256, 0, stream>>>(pf, pf + (size_t)MROWS * D_MODEL, out, out, N8);
  } else {
    // fallback: round-2 verified path (80 MiB)
    short* qb = (short*)(ws + ((size_t)0  << 20));
    short* kb = (short*)(ws + ((size_t)16 << 20));
    short* vb = (short*)(ws + ((size_t)32 << 20));
    short* ab = (short*)(ws + ((size_t)48 << 20));
    short* xn = (short*)(ws + ((size_t)64 << 20));
    short* hb = (short*)(ws + ((size_t)0  << 20));

    dim3 gproj(MROWS / 128, D_MODEL / 128);
    rmsnorm_k<<<MROWS, 256, 0, stream>>>(x, g1, xn);
    gemm_bt<0><<<gproj, 256, 0, stream>>>(xn, wq, qb, nullptr, MROWS, D_MODEL, D_MODEL);
    gemm_bt<0><<<gproj, 256, 0, stream>>>(xn, wk, kb, nullptr, MROWS, D_MODEL, D_MODEL);
    gemm_bt<0><<<gproj, 256, 0, stream>>>(xn, wv, vb, nullptr, MROWS, D_MODEL, D_MODEL);
    attn_k<<<dim3(SEQ / 128, BATCH * NHEAD), 256, 0, stream>>>(qb, kb, vb, ab);
    gemm_bt<2><<<gproj, 256, 0, stream>>>(ab, wo, out, x, MROWS, D_MODEL, D_MODEL);
    rmsnorm_k<<<MROWS, 256, 0, stream>>>(out, g2, xn);
    for (int half = 0; half < 2; ++half) {
      const short* xh = xn  + (size_t)half * 2048 * D_MODEL;
      float*       oh = out + (size_t)half * 2048 * D_MODEL;
      gemm_bt<1><<<dim3(2048 / 128, DFF / 128), 256, 0, stream>>>(xh, w1, hb, nullptr, 2048, DFF, D_MODEL);
      gemm_bt<2><<<dim3(2048 / 128, D_MODEL / 128), 256, 0, stream>>>(hb, w2, oh, oh, 2048, D_MODEL, DFF);
    }
  }
}

// Round 13
// 749.085 us; speedup vs baseline: 4.5865x; 1.5159x over previous
//
#include <hip/hip_runtime.h>
#include <hip/hip_bf16.h>
#include <math.h>

// ---- problem constants ----
#define D_MODEL 2048
#define SEQ     2048
#define BATCH   2
#define NHEAD   16
#define DK      128
#define DFF     8192
#define MROWS   (BATCH*SEQ)   // 4096 rows

typedef short short8 __attribute__((ext_vector_type(8)));   // 8 bf16 in 4 VGPRs
typedef float f32x4  __attribute__((ext_vector_type(4)));

__device__ __forceinline__ short f2bf(float f) {
  union { __hip_bfloat16 b; short s; } u;
  u.b = __float2bfloat16(f);
  return u.s;
}
__device__ __forceinline__ float bf2f(short s) {
  union { unsigned u; float f; } u;
  u.u = ((unsigned)(unsigned short)s) << 16;
  return u.f;
}

#define MF(a, b, c) __builtin_amdgcn_mfma_f32_16x16x32_bf16(a, b, c, 0, 0, 0)

__device__ __forceinline__ void gload_lds16(const void* g, void* l) {
  __builtin_amdgcn_global_load_lds(
      (const __attribute__((address_space(1))) unsigned int*)g,
      (__attribute__((address_space(3))) unsigned int*)l, 16, 0, 0);
}

// ---------------- RMSNorm: fp32 in -> bf16 out ----------------
__global__ __launch_bounds__(256) void rmsnorm_k(const float* __restrict__ x,
                                                 const float* __restrict__ g,
                                                 short* __restrict__ o) {
  const int row = blockIdx.x;
  const int t = threadIdx.x;
  const float4* xr = (const float4*)(x + (size_t)row * D_MODEL);
  const float4* gr = (const float4*)g;
  float4 v0 = xr[2*t], v1 = xr[2*t+1];
  float s = v0.x*v0.x + v0.y*v0.y + v0.z*v0.z + v0.w*v0.w
          + v1.x*v1.x + v1.y*v1.y + v1.z*v1.z + v1.w*v1.w;
  #pragma unroll
  for (int off = 1; off < 64; off <<= 1) s += __shfl_xor(s, off);
  __shared__ float red[4];
  if ((t & 63) == 0) red[t >> 6] = s;
  __syncthreads();
  float tot = red[0] + red[1] + red[2] + red[3];
  float inv = rsqrtf(tot * (1.0f / D_MODEL) + 1e-5f);
  float4 g0 = gr[2*t], g1v = gr[2*t+1];
  short8 ov;
  ov[0] = f2bf(v0.x * inv * g0.x);
  ov[1] = f2bf(v0.y * inv * g0.y);
  ov[2] = f2bf(v0.z * inv * g0.z);
  ov[3] = f2bf(v0.w * inv * g0.w);
  ov[4] = f2bf(v1.x * inv * g1v.x);
  ov[5] = f2bf(v1.y * inv * g1v.y);
  ov[6] = f2bf(v1.z * inv * g1v.z);
  ov[7] = f2bf(v1.w * inv * g1v.w);
  *((short8*)(o + (size_t)row * D_MODEL) + t) = ov;
}

// ---------------- fp32 -> bf16 convert (weights, one-time) ----------------
__global__ __launch_bounds__(256) void f2b_k(const float* __restrict__ src,
                                             short* __restrict__ dst, int n8) {
  int i = blockIdx.x * 256 + threadIdx.x;
  if (i >= n8) return;
  const float4* s4 = (const float4*)src + 2 * (size_t)i;
  float4 a = s4[0], b = s4[1];
  short8 o = { f2bf(a.x), f2bf(a.y), f2bf(a.z), f2bf(a.w),
               f2bf(b.x), f2bf(b.y), f2bf(b.z), f2bf(b.w) };
  *((short8*)dst + i) = o;
}

// ---------------- split-K combine: o = bf16(p0) + bf16(p1) + fp32(r) ----------------
__global__ __launch_bounds__(256) void combine_bb(const short* __restrict__ p0,
                                                  const short* __restrict__ p1,
                                                  const float* __restrict__ r,
                                                  float* __restrict__ o, int n8) {
  int i = blockIdx.x * 256 + threadIdx.x;
  if (i >= n8) return;
  short8 a = ((const short8*)p0)[i];
  short8 b = ((const short8*)p1)[i];
  float4 r0 = ((const float4*)r)[2 * (size_t)i];
  float4 r1 = ((const float4*)r)[2 * (size_t)i + 1];
  float4 o0, o1;
  o0.x = bf2f(a[0]) + bf2f(b[0]) + r0.x;
  o0.y = bf2f(a[1]) + bf2f(b[1]) + r0.y;
  o0.z = bf2f(a[2]) + bf2f(b[2]) + r0.z;
  o0.w = bf2f(a[3]) + bf2f(b[3]) + r0.w;
  o1.x = bf2f(a[4]) + bf2f(b[4]) + r1.x;
  o1.y = bf2f(a[5]) + bf2f(b[5]) + r1.y;
  o1.z = bf2f(a[6]) + bf2f(b[6]) + r1.z;
  o1.w = bf2f(a[7]) + bf2f(b[7]) + r1.w;
  ((float4*)o)[2 * (size_t)i]     = o0;
  ((float4*)o)[2 * (size_t)i + 1] = o1;
}

// ---- fused: x2 = bf16(p0)+bf16(p1)+x (fp32, ->out) ; xn = rmsnorm(x2, g) bf16 ----
__global__ __launch_bounds__(256) void combine_rms(const short* __restrict__ p0,
                                                   const short* __restrict__ p1,
                                                   const float* __restrict__ xres,
                                                   const float* __restrict__ g,
                                                   float* __restrict__ out,
                                                   short* __restrict__ xn) {
  const int row = blockIdx.x;
  const int t = threadIdx.x;
  const size_t b8 = (size_t)row * (D_MODEL / 8) + t;
  short8 a = ((const short8*)p0)[b8];
  short8 b = ((const short8*)p1)[b8];
  float4 r0 = ((const float4*)xres)[2 * b8];
  float4 r1 = ((const float4*)xres)[2 * b8 + 1];
  float v[8];
  v[0] = bf2f(a[0]) + bf2f(b[0]) + r0.x;
  v[1] = bf2f(a[1]) + bf2f(b[1]) + r0.y;
  v[2] = bf2f(a[2]) + bf2f(b[2]) + r0.z;
  v[3] = bf2f(a[3]) + bf2f(b[3]) + r0.w;
  v[4] = bf2f(a[4]) + bf2f(b[4]) + r1.x;
  v[5] = bf2f(a[5]) + bf2f(b[5]) + r1.y;
  v[6] = bf2f(a[6]) + bf2f(b[6]) + r1.z;
  v[7] = bf2f(a[7]) + bf2f(b[7]) + r1.w;
  float4 o0 = {v[0], v[1], v[2], v[3]}, o1 = {v[4], v[5], v[6], v[7]};
  ((float4*)out)[2 * b8]     = o0;
  ((float4*)out)[2 * b8 + 1] = o1;
  float s = 0.f;
  #pragma unroll
  for (int j = 0; j < 8; ++j) s += v[j] * v[j];
  #pragma unroll
  for (int off = 1; off < 64; off <<= 1) s += __shfl_xor(s, off);
  __shared__ float red[4];
  if ((t & 63) == 0) red[t >> 6] = s;
  __syncthreads();
  float tot = red[0] + red[1] + red[2] + red[3];
  float inv = rsqrtf(tot * (1.0f / D_MODEL) + 1e-5f);
  float4 g0 = ((const float4*)g)[2 * t], g1v = ((const float4*)g)[2 * t + 1];
  short8 ov;
  ov[0] = f2bf(v[0] * inv * g0.x);
  ov[1] = f2bf(v[1] * inv * g0.y);
  ov[2] = f2bf(v[2] * inv * g0.z);
  ov[3] = f2bf(v[3] * inv * g0.w);
  ov[4] = f2bf(v[4] * inv * g1v.x);
  ov[5] = f2bf(v[5] * inv * g1v.y);
  ov[6] = f2bf(v[6] * inv * g1v.z);
  ov[7] = f2bf(v[7] * inv * g1v.w);
  ((short8*)xn)[b8] = ov;
}

// ======== 256x128 single-buffer GEMM, 128x64 WAVE tile, 2 blocks/CU ========
// C[M,N] = A[M,K](bf16) * B[N,K](bf16)^T. 256 thr = 4 waves (2M x 2N), wave 128x64
// (acc[8][4]: A-frag reuse across 4 B-frags -> 0.5625 KB LDS/MFMA, cap ~80%).
// launch_bounds(256,2): 2 waves/SIMD -> 256-reg unified budget; acc(128 AGPR)
// + frags/addr (~70) fits with NO SPILL (R12's (256,3)=170 budget spilled:
// WRITE_SIZE 85->382 MB, MfmaUtil 13%). LDS = 48 KB single buffer, 2 blocks/CU:
// independent barrier domains cover the per-tile drain. m97-exact control flow,
// builtin global_load_lds (compiler-inserted waits), XOR swizzle both sides
// -> 0 bank conflicts. EPI: 0 bf16; 1 GELU bf16; 2 +resid fp32.
// SPLIT: split-K x2, bf16 partials at Cv + ks*M*N.
template<int EPI, int SPLIT>
__global__ __launch_bounds__(256, 2) void gemm256x128(const short* __restrict__ A,
                                                      const short* __restrict__ Bp,
                                                      void* Cv,
                                                      const float* __restrict__ resid,
                                                      int M, int N, int Kloop,
                                                      int lda, int nbx) {
  __shared__ __align__(16) short As[256 * 64];   // 32 KB
  __shared__ __align__(16) short Bs[128 * 64];   // 16 KB
  const int nk = Kloop >> 6;
  const int cpx = gridDim.x >> 3;                // grid % 8 == 0 (bijective XCD swizzle)
  const int lin = (blockIdx.x & 7) * cpx + (blockIdx.x >> 3);
  const int bx = lin % nbx;
  int row2 = lin / nbx, by, ks = 0;
  if (SPLIT) { ks = row2 & 1; by = row2 >> 1; } else { by = row2; }
  const int m0 = bx * 256, n0 = by * 128;
  if (SPLIT) { A += (size_t)ks * Kloop; Bp += (size_t)ks * Kloop; }

  const int t = threadIdx.x, w = t >> 6, lane = t & 63, lr = lane & 15, lg = lane >> 4;
  const int wm = w >> 1, wn = w & 1;             // wave tile: rows wm*128..+128, cols wn*64..+64

  // staging: thread t -> rows r+32i, 16B chunk c8; source col pre-swizzled
  const int r = t >> 3, c8 = t & 7;
  const int swc = (c8 ^ (r & 7)) << 3;           // (r+32i)&7 == r&7
  const short* pA = A  + (size_t)(m0 + r) * lda + swc;
  const short* pB = Bp + (size_t)(n0 + r) * lda + swc;
  const size_t l32 = (size_t)32 * lda;

  f32x4 acc[8][4];
  const f32x4 z4 = {0.f, 0.f, 0.f, 0.f};
  #pragma unroll
  for (int m = 0; m < 8; ++m)
    #pragma unroll
    for (int n = 0; n < 4; ++n) acc[m][n] = z4;

  const int rsw = (lr & 7) << 3;                 // lane-constant read swizzle (shorts)

  for (int T = 0; T < nk; ++T) {
    // ---- stage tile T: A 8 chunks (256 rows), B 4 chunks (128 rows) ----
    #pragma unroll
    for (int i = 0; i < 8; ++i)
      gload_lds16(pA + (size_t)T * 64 + i * l32, &As[i * 2048 + w * 512]);
    #pragma unroll
    for (int i = 0; i < 4; ++i)
      gload_lds16(pB + (size_t)T * 64 + i * l32, &Bs[i * 2048 + w * 512]);
    __syncthreads();

    // ---- compute tile T: per k-half, 8 A-frags reused over 4 B-frags ----
    #pragma unroll
    for (int kk = 0; kk < 2; ++kk) {
      short8 af[8];
      #pragma unroll
      for (int m = 0; m < 8; ++m) {
        int ar = wm * 128 + m * 16 + lr;
        af[m] = *(const short8*)&As[ar * 64 + ((kk * 32 + lg * 8) ^ rsw)];
      }
      #pragma unroll
      for (int n = 0; n < 4; ++n) {
        int br = wn * 64 + n * 16 + lr;
        short8 bf = *(const short8*)&Bs[br * 64 + ((kk * 32 + lg * 8) ^ rsw)];
        #pragma unroll
        for (int m = 0; m < 8; ++m) acc[m][n] = MF(af[m], bf, acc[m][n]);
      }
    }
    if (T + 1 < nk) __syncthreads();   // reads done before next stage overwrites
  }

  // ---- epilogue ----
  short* Cs = (short*)Cv;
  if (SPLIT) Cs += (size_t)ks * ((size_t)M * N);
  #pragma unroll
  for (int m = 0; m < 8; ++m)
    #pragma unroll
    for (int n = 0; n < 4; ++n)
      #pragma unroll
      for (int rr = 0; rr < 4; ++rr) {
        int row = m0 + wm * 128 + m * 16 + lg * 4 + rr;
        int col = n0 + wn * 64 + n * 16 + lr;
        size_t idx = (size_t)row * N + col;
        float vv = acc[m][n][rr];
        if (EPI == 0) {
          Cs[idx] = f2bf(vv);
        } else if (EPI == 1) {
          float gl = 0.5f * vv * (1.0f + erff(vv * 0.70710678118654752f));
          ((short*)Cv)[idx] = f2bf(gl);
        } else {
          ((float*)Cv)[idx] = vv + resid[idx];
        }
      }
}

// ---------------- V transpose: qkv[.., v cols] -> vt[b][h][d][s] ----------------
__global__ __launch_bounds__(256) void vtrans(const short* __restrict__ QKV,
                                              short* __restrict__ VT) {
  const int st = blockIdx.x;   // s tile of 64
  const int bh = blockIdx.y;
  const int b = bh >> 4, h = bh & 15;
  const int t = threadIdx.x;
  __shared__ __align__(16) short T[64 * 128];
  const short* Vsrc = QKV + ((size_t)b * SEQ) * 6144 + 2 * D_MODEL + h * DK;
  {
    int r = t >> 4, c = (t & 15) * 8;
    #pragma unroll
    for (int i = 0; i < 4; ++i) {
      int rr = r + 16 * i;
      uint4 vv = *(const uint4*)(Vsrc + (size_t)(st * 64 + rr) * 6144 + c);
      *(uint4*)&T[rr * 128 + (c ^ (((rr >> 3) & 7) << 3))] = vv;
    }
  }
  __syncthreads();
  short* dst = VT + ((size_t)bh * DK) * SEQ + st * 64;
  {
    int c2 = (t & 7) * 8;
    #pragma unroll
    for (int i = 0; i < 4; ++i) {
      int d = (t >> 3) + 32 * i;
      short8 ov;
      #pragma unroll
      for (int j = 0; j < 8; ++j)
        ov[j] = T[(c2 + j) * 128 + (d ^ ((((c2 + j) >> 3) & 7) << 3))];
      *(short8*)(dst + (size_t)d * SEQ + c2) = ov;
    }
  }
}

// ---------------- Flash attention v3 (round-4 verified) ----------------
__global__ __launch_bounds__(512, 2) void attn3(const short* __restrict__ QKV,
                                                const short* __restrict__ VT,
                                                short* __restrict__ O) {
  const float SC = 0.12751743f;   // (1/sqrt(128)) * log2(e)
  const int a = blockIdx.x, bh = blockIdx.y;
  const int b = bh >> 4, h = bh & 15;
  const int t = threadIdx.x, w = t >> 6, lane = t & 63, lr = lane & 15, lg = lane >> 4;
  const short* Qp = QKV + ((size_t)b * SEQ) * 6144 + h * DK;
  const short* Kp = Qp + D_MODEL;
  const short* Vp = VT + ((size_t)bh * DK) * SEQ;   // [d][s]
  __shared__ __align__(16) short Ks[2][64 * 128];
  __shared__ __align__(16) short Vs[2][128 * 64];
  __shared__ __align__(16) short Ps[8][16][72];

  const int krr = t >> 4, kcc = (t & 15) * 8;
  const int vdd = t >> 3, vcc = (t & 7) * 8;
  const f32x4 z4 = {0.f, 0.f, 0.f, 0.f};

  for (int sub = 0; sub < 2; ++sub) {
    const int ts = sub ? (15 - a) : a;
    const int nt = 2 * ts + 2;
    const int qrow0 = ts * 128 + w * 16;

    short8 qf[4];
    #pragma unroll
    for (int ki = 0; ki < 4; ++ki)
      qf[ki] = *(const short8*)(Qp + (size_t)(qrow0 + lr) * 6144 + ki * 32 + lg * 8);

    f32x4 acc[8];
    #pragma unroll
    for (int nd = 0; nd < 8; ++nd) acc[nd] = z4;
    float mrow[4], lsum[4];
    #pragma unroll
    for (int r = 0; r < 4; ++r) { mrow[r] = -INFINITY; lsum[r] = 0.f; }

    uint4 krg[2], vrg[2];
    #pragma unroll
    for (int i = 0; i < 2; ++i) {
      krg[i] = *(const uint4*)(Kp + (size_t)(krr + 32 * i) * 6144 + kcc);
      vrg[i] = *(const uint4*)(Vp + (size_t)(vdd + 64 * i) * SEQ + vcc);
    }
    __syncthreads();
    #pragma unroll
    for (int i = 0; i < 2; ++i) {
      int r = krr + 32 * i;
      *(uint4*)&Ks[0][(r * 128 + kcc) ^ ((r & 7) << 3)] = krg[i];
      int d = vdd + 64 * i;
      *(uint4*)&Vs[0][(d * 64 + vcc) ^ ((d & 7) << 3)] = vrg[i];
    }
    __syncthreads();

    int cur = 0;
    for (int tt = 0; tt < nt; ++tt) {
      const bool pre = (tt + 1 < nt);
      if (pre) {
        #pragma unroll
        for (int i = 0; i < 2; ++i) {
          krg[i] = *(const uint4*)(Kp + (size_t)((tt + 1) * 64 + krr + 32 * i) * 6144 + kcc);
          vrg[i] = *(const uint4*)(Vp + (size_t)(vdd + 64 * i) * SEQ + (tt + 1) * 64 + vcc);
        }
      }

      f32x4 sf[4] = {z4, z4, z4, z4};
      #pragma unroll
      for (int ki = 0; ki < 4; ++ki) {
        #pragma unroll
        for (int nk = 0; nk < 4; ++nk) {
          int rr = nk * 16 + lr;
          short8 kf = *(const short8*)&Ks[cur][(rr * 128 + ki * 32 + lg * 8) ^ ((rr & 7) << 3)];
          sf[nk] = MF(qf[ki], kf, sf[nk]);
        }
      }

      const bool diag = (tt * 64 + 63 > qrow0);
      #pragma unroll
      for (int r = 0; r < 4; ++r) {
        int qg = qrow0 + lg * 4 + r;
        float s0 = sf[0][r] * SC, s1 = sf[1][r] * SC, s2 = sf[2][r] * SC, s3 = sf[3][r] * SC;
        if (diag) {
          int c0 = tt * 64 + lr;
          s0 = (c0      <= qg) ? s0 : -3.0e38f;
          s1 = (c0 + 16 <= qg) ? s1 : -3.0e38f;
          s2 = (c0 + 32 <= qg) ? s2 : -3.0e38f;
          s3 = (c0 + 48 <= qg) ? s3 : -3.0e38f;
        }
        float mx = fmaxf(fmaxf(s0, s1), fmaxf(s2, s3));
        mx = fmaxf(mx, __shfl_xor(mx, 1));
        mx = fmaxf(mx, __shfl_xor(mx, 2));
        mx = fmaxf(mx, __shfl_xor(mx, 4));
        mx = fmaxf(mx, __shfl_xor(mx, 8));
        float mnew = fmaxf(mrow[r], mx);
        float alpha = exp2f(mrow[r] - mnew);
        mrow[r] = mnew;
        float p0 = exp2f(s0 - mnew), p1 = exp2f(s1 - mnew),
              p2 = exp2f(s2 - mnew), p3 = exp2f(s3 - mnew);
        lsum[r] = lsum[r] * alpha + ((p0 + p1) + (p2 + p3));
        #pragma unroll
        for (int nd = 0; nd < 8; ++nd) acc[nd][r] *= alpha;
        short* pr = &Ps[w][lg * 4 + r][0];
        pr[lr]      = f2bf(p0);
        pr[16 + lr] = f2bf(p1);
        pr[32 + lr] = f2bf(p2);
        pr[48 + lr] = f2bf(p3);
      }
      asm volatile("s_waitcnt lgkmcnt(0)" ::: "memory");
      __builtin_amdgcn_sched_barrier(0);

      short8 pf0 = *(const short8*)&Ps[w][lr][lg * 8];
      short8 pf1 = *(const short8*)&Ps[w][lr][32 + lg * 8];
      #pragma unroll
      for (int nd = 0; nd < 8; ++nd) {
        int rr = nd * 16 + lr;
        short8 vf0 = *(const short8*)&Vs[cur][(rr * 64 + lg * 8) ^ ((rr & 7) << 3)];
        short8 vf1 = *(const short8*)&Vs[cur][(rr * 64 + 32 + lg * 8) ^ ((rr & 7) << 3)];
        acc[nd] = MF(pf0, vf0, acc[nd]);
        acc[nd] = MF(pf1, vf1, acc[nd]);
      }
      __syncthreads();
      if (pre) {
        #pragma unroll
        for (int i = 0; i < 2; ++i) {
          int r = krr + 32 * i;
          *(uint4*)&Ks[cur ^ 1][(r * 128 + kcc) ^ ((r & 7) << 3)] = krg[i];
          int d = vdd + 64 * i;
          *(uint4*)&Vs[cur ^ 1][(d * 64 + vcc) ^ ((d & 7) << 3)] = vrg[i];
        }
      }
      __syncthreads();
      cur ^= 1;
    }

    float inv[4];
    #pragma unroll
    for (int r = 0; r < 4; ++r) {
      float ls = lsum[r];
      ls += __shfl_xor(ls, 1);
      ls += __shfl_xor(ls, 2);
      ls += __shfl_xor(ls, 4);
      ls += __shfl_xor(ls, 8);
      inv[r] = 1.0f / ls;
    }
    #pragma unroll
    for (int nd = 0; nd < 8; ++nd)
      #pragma unroll
      for (int r = 0; r < 4; ++r) {
        int row = qrow0 + lg * 4 + r;
        O[(size_t)(b * SEQ + row) * D_MODEL + h * DK + nd * 16 + lr] = f2bf(acc[nd][r] * inv[r]);
      }
  }
}

// ======== FALLBACK PATH (round-2 verified kernels) ========
template<int EPI>
__global__ __launch_bounds__(256) void gemm_bt(const short* __restrict__ A,
                                               const float* __restrict__ B,
                                               void* Cv,
                                               const float* resid,
                                               int M, int N, int K) {
  __shared__ __align__(16) short As[128][72];
  __shared__ __align__(16) short Bs[128][72];
  const int t = threadIdx.x;
  const int m0 = blockIdx.x * 128, n0 = blockIdx.y * 128;
  const int wave = t >> 6, lane = t & 63, lr = lane & 15, lg = lane >> 4;
  const int wr = (wave >> 1) * 64, wc = (wave & 1) * 64;

  f32x4 acc[4][4];
  const f32x4 z4 = {0.f, 0.f, 0.f, 0.f};
  #pragma unroll
  for (int m = 0; m < 4; ++m)
    #pragma unroll
    for (int n = 0; n < 4; ++n) acc[m][n] = z4;

  int ar[4], ac[4];
  #pragma unroll
  for (int i = 0; i < 4; ++i) { int u = t + 256*i; ar[i] = u >> 3; ac[i] = (u & 7) * 8; }

  for (int k0 = 0; k0 < K; k0 += 64) {
    #pragma unroll
    for (int i = 0; i < 4; ++i) {
      uint4 va = *(const uint4*)(A + (size_t)(m0 + ar[i]) * K + k0 + ac[i]);
      *(uint4*)&As[ar[i]][ac[i]] = va;
    }
    #pragma unroll
    for (int i = 0; i < 4; ++i) {
      const float4* bp = (const float4*)(B + (size_t)(n0 + ar[i]) * K + k0 + ac[i]);
      float4 b0 = bp[0], b1 = bp[1];
      short8 pb = { f2bf(b0.x), f2bf(b0.y), f2bf(b0.z), f2bf(b0.w),
                    f2bf(b1.x), f2bf(b1.y), f2bf(b1.z), f2bf(b1.w) };
      *(short8*)&Bs[ar[i]][ac[i]] = pb;
    }
    __syncthreads();
    #pragma unroll
    for (int kk = 0; kk < 64; kk += 32) {
      short8 af[4], bfr[4];
      #pragma unroll
      for (int m = 0; m < 4; ++m) af[m]  = *(const short8*)&As[wr + m*16 + lr][kk + lg*8];
      #pragma unroll
      for (int n = 0; n < 4; ++n) bfr[n] = *(const short8*)&Bs[wc + n*16 + lr][kk + lg*8];
      #pragma unroll
      for (int m = 0; m < 4; ++m)
        #pragma unroll
        for (int n = 0; n < 4; ++n)
          acc[m][n] = MF(af[m], bfr[n], acc[m][n]);
    }
    __syncthreads();
  }

  #pragma unroll
  for (int m = 0; m < 4; ++m)
    #pragma unroll
    for (int n = 0; n < 4; ++n)
      #pragma unroll
      for (int r = 0; r < 4; ++r) {
        int row = m0 + wr + m*16 + lg*4 + r;
        int col = n0 + wc + n*16 + lr;
        size_t idx = (size_t)row * N + col;
        float vv = acc[m][n][r];
        if (EPI == 0) {
          ((short*)Cv)[idx] = f2bf(vv);
        } else if (EPI == 1) {
          float gl = 0.5f * vv * (1.0f + erff(vv * 0.70710678118654752f));
          ((short*)Cv)[idx] = f2bf(gl);
        } else {
          ((float*)Cv)[idx] = vv + resid[idx];
        }
      }
}

__global__ __launch_bounds__(256) void attn_k(const short* __restrict__ Q,
                                              const short* __restrict__ K,
                                              const short* __restrict__ V,
                                              short* __restrict__ O) {
  const float scale = 0.08838834764831845f;
  const int qt = blockIdx.x;
  const int bh = blockIdx.y;
  const int b = bh >> 4, h = bh & 15;
  const size_t base = ((size_t)b * SEQ) * D_MODEL + (size_t)h * DK;
  const int t = threadIdx.x, wave = t >> 6, lane = t & 63, lr = lane & 15, lg = lane >> 4;

  __shared__ __align__(16) short Ks[32][136];
  __shared__ __align__(16) short Vt[128][40];
  __shared__ __align__(16) short Ps[4][32][40];

  const int qrow0 = qt * 128 + wave * 32;
  short8 qf[2][4];
  #pragma unroll
  for (int mq = 0; mq < 2; ++mq)
    #pragma unroll
    for (int ki = 0; ki < 4; ++ki)
      qf[mq][ki] = *(const short8*)(Q + base + (size_t)(qrow0 + mq*16 + lr) * D_MODEL + ki*32 + lg*8);

  f32x4 acc[2][8];
  const f32x4 z4 = {0.f, 0.f, 0.f, 0.f};
  #pragma unroll
  for (int mq = 0; mq < 2; ++mq)
    #pragma unroll
    for (int nd = 0; nd < 8; ++nd) acc[mq][nd] = z4;
  float mrow[2][4], lsum[2][4];
  #pragma unroll
  for (int mq = 0; mq < 2; ++mq)
    #pragma unroll
    for (int r = 0; r < 4; ++r) { mrow[mq][r] = -INFINITY; lsum[mq][r] = 0.f; }

  const int lastt = qt * 4 + 3;
  for (int tt = 0; tt <= lastt; ++tt) {
    #pragma unroll
    for (int i = 0; i < 2; ++i) {
      int u = t + 256*i; int r = u >> 4; int c = (u & 15) * 8;
      *(uint4*)&Ks[r][c] = *(const uint4*)(K + base + (size_t)(tt*32 + r) * D_MODEL + c);
      uint4 vv = *(const uint4*)(V + base + (size_t)(tt*32 + r) * D_MODEL + c);
      const short* sv = (const short*)&vv;
      #pragma unroll
      for (int j = 0; j < 8; ++j) Vt[c + j][r] = sv[j];
    }
    __syncthreads();
    if (tt <= qt * 4 + wave) {
      f32x4 sf[2][2] = {{z4, z4}, {z4, z4}};
      #pragma unroll
      for (int ki = 0; ki < 4; ++ki) {
        short8 kf0 = *(const short8*)&Ks[lr][ki*32 + lg*8];
        short8 kf1 = *(const short8*)&Ks[16 + lr][ki*32 + lg*8];
        sf[0][0] = MF(qf[0][ki], kf0, sf[0][0]);
        sf[0][1] = MF(qf[0][ki], kf1, sf[0][1]);
        sf[1][0] = MF(qf[1][ki], kf0, sf[1][0]);
        sf[1][1] = MF(qf[1][ki], kf1, sf[1][1]);
      }
      #pragma unroll
      for (int mq = 0; mq < 2; ++mq) {
        #pragma unroll
        for (int r = 0; r < 4; ++r) {
          int qg = qrow0 + mq*16 + lg*4 + r;
          float s0 = sf[mq][0][r] * scale;
          float s1 = sf[mq][1][r] * scale;
          if (tt*32 + lr > qg)       s0 = -INFINITY;
          if (tt*32 + 16 + lr > qg)  s1 = -INFINITY;
          float mx = fmaxf(s0, s1);
          mx = fmaxf(mx, __shfl_xor(mx, 1));
          mx = fmaxf(mx, __shfl_xor(mx, 2));
          mx = fmaxf(mx, __shfl_xor(mx, 4));
          mx = fmaxf(mx, __shfl_xor(mx, 8));
          float mnew = fmaxf(mrow[mq][r], mx);
          float alpha = __expf(mrow[mq][r] - mnew);
          mrow[mq][r] = mnew;
          float p0 = __expf(s0 - mnew);
          float p1 = __expf(s1 - mnew);
          float ps = p0 + p1;
          ps += __shfl_xor(ps, 1);
          ps += __shfl_xor(ps, 2);
          ps += __shfl_xor(ps, 4);
          ps += __shfl_xor(ps, 8);
          lsum[mq][r] = lsum[mq][r] * alpha + ps;
          #pragma unroll
          for (int nd = 0; nd < 8; ++nd) acc[mq][nd][r] *= alpha;
          Ps[wave][mq*16 + lg*4 + r][lr]      = f2bf(p0);
          Ps[wave][mq*16 + lg*4 + r][16 + lr] = f2bf(p1);
        }
      }
      asm volatile("s_waitcnt lgkmcnt(0)" ::: "memory");
      short8 pf0 = *(const short8*)&Ps[wave][lr][lg*8];
      short8 pf1 = *(const short8*)&Ps[wave][16 + lr][lg*8];
      #pragma unroll
      for (int nd = 0; nd < 8; ++nd) {
        short8 vf = *(const short8*)&Vt[nd*16 + lr][lg*8];
        acc[0][nd] = MF(pf0, vf, acc[0][nd]);
        acc[1][nd] = MF(pf1, vf, acc[1][nd]);
      }
    }
    __syncthreads();
  }

  #pragma unroll
  for (int mq = 0; mq < 2; ++mq)
    #pragma unroll
    for (int nd = 0; nd < 8; ++nd)
      #pragma unroll
      for (int r = 0; r < 4; ++r) {
        int row = qrow0 + mq*16 + lg*4 + r;
        O[base + (size_t)row * D_MODEL + nd*16 + lr] = f2bf(acc[mq][nd][r] / lsum[mq][r]);
      }
}

// ---------------- launch ----------------
extern "C" void kernel_launch(void* const* d_in, const int* in_sizes, int n_in,
                              void* d_out, int out_size, void* d_ws, size_t ws_size,
                              hipStream_t stream) {
  const float* x  = (const float*)d_in[0];
  const float* wq = (const float*)d_in[1];
  const float* wk = (const float*)d_in[2];
  const float* wv = (const float*)d_in[3];
  const float* wo = (const float*)d_in[4];
  const float* w1 = (const float*)d_in[5];
  const float* w2 = (const float*)d_in[6];
  const float* g1 = (const float*)d_in[7];
  const float* g2 = (const float*)d_in[8];
  float* out = (float*)d_out;
  char* ws = (char*)d_ws;

  const size_t NEED = (size_t)192 << 20;
  if (ws_size >= NEED) {
    // fast path layout (192 MiB):
    //   [0,24M) wqkv | [24,32M) wo | [32,64M) w1 | [64,96M) w2   (bf16 weights)
    //   [96,144M) qkv | [144,160M) vt | [160,176M) ab | [176,192M) xn
    //   oproj phase: partials (2x16M bf16) at [96,128)   (qkv/vt dead)
    //   FFN phase:   hb = [96,160M); FFN2 partials (2x16M bf16) at [160,192) (ab/xn dead)
    short* wqkv = (short*)(ws);
    short* wo_b = (short*)(ws + ((size_t)24 << 20));
    short* w1_b = (short*)(ws + ((size_t)32 << 20));
    short* w2_b = (short*)(ws + ((size_t)64 << 20));
    short* qkv  = (short*)(ws + ((size_t)96 << 20));
    short* vt   = (short*)(ws + ((size_t)144 << 20));
    short* ab   = (short*)(ws + ((size_t)160 << 20));
    short* xn   = (short*)(ws + ((size_t)176 << 20));
    short* hb   = (short*)(ws + ((size_t)96 << 20));
    short* po   = (short*)(ws + ((size_t)96 << 20));    // oproj partials (2x MROWSxD bf16)
    short* pf   = (short*)(ws + ((size_t)160 << 20));   // FFN2 partials (2x MROWSxD bf16)

    const int NW = D_MODEL * D_MODEL / 8;
    f2b_k<<<(NW + 255) / 256, 256, 0, stream>>>(wq, wqkv,                   NW);
    f2b_k<<<(NW + 255) / 256, 256, 0, stream>>>(wk, wqkv + (size_t)D_MODEL * D_MODEL,     NW);
    f2b_k<<<(NW + 255) / 256, 256, 0, stream>>>(wv, wqkv + (size_t)2 * D_MODEL * D_MODEL, NW);
    f2b_k<<<(NW + 255) / 256, 256, 0, stream>>>(wo, wo_b, NW);
    const int NF = DFF * D_MODEL / 8;
    f2b_k<<<(NF + 255) / 256, 256, 0, stream>>>(w1, w1_b, NF);
    f2b_k<<<(NF + 255) / 256, 256, 0, stream>>>(w2, w2_b, NF);

    const int N8 = MROWS * D_MODEL / 8;

    rmsnorm_k<<<MROWS, 256, 0, stream>>>(x, g1, xn);
    // QKV: (4096/256)x(6144/128) = 16x48 = 768 blocks
    gemm256x128<0,0><<<dim3(16 * 48), 256, 0, stream>>>(xn, wqkv, qkv, nullptr,
                                                        MROWS, 6144, D_MODEL, D_MODEL, 16);
    vtrans<<<dim3(SEQ/64, BATCH*NHEAD), 256, 0, stream>>>(qkv, vt);
    attn3<<<dim3(8, BATCH*NHEAD), 512, 0, stream>>>(qkv, vt, ab);
    // o-proj: split-K x2 -> 16x16x2 = 512 blocks, bf16 partials; fused combine+resid+rmsnorm2
    gemm256x128<0,1><<<dim3(16 * 16 * 2), 256, 0, stream>>>(ab, wo_b, po, nullptr,
                                                            MROWS, D_MODEL, D_MODEL / 2, D_MODEL, 16);
    combine_rms<<<MROWS, 256, 0, stream>>>(po, po + (size_t)MROWS * D_MODEL, x, g2, out, xn);
    // FFN1: 16x64 = 1024 blocks, GELU
    gemm256x128<1,0><<<dim3(16 * 64), 256, 0, stream>>>(xn, w1_b, hb, nullptr,
                                                        MROWS, DFF, D_MODEL, D_MODEL, 16);
    // FFN2: split-K x2 -> 512 blocks, bf16 partials; combine in-place with resid out
    gemm256x128<0,1><<<dim3(16 * 16 * 2), 256, 0, stream>>>(hb, w2_b, pf, nullptr,
                                                            MROWS, D_MODEL, DFF / 2, DFF, 16);
    combine_bb<<<(N8 + 255) / 256, 256, 0, stream>>>(pf, pf + (size_t)MROWS * D_MODEL, out, out, N8);
  } else {
    // fallback: round-2 verified path (80 MiB)
    short* qb = (short*)(ws + ((size_t)0  << 20));
    short* kb = (short*)(ws + ((size_t)16 << 20));
    short* vb = (short*)(ws + ((size_t)32 << 20));
    short* ab = (short*)(ws + ((size_t)48 << 20));
    short* xn = (short*)(ws + ((size_t)64 << 20));
    short* hb = (short*)(ws + ((size_t)0  << 20));

    dim3 gproj(MROWS / 128, D_MODEL / 128);
    rmsnorm_k<<<MROWS, 256, 0, stream>>>(x, g1, xn);
    gemm_bt<0><<<gproj, 256, 0, stream>>>(xn, wq, qb, nullptr, MROWS, D_MODEL, D_MODEL);
    gemm_bt<0><<<gproj, 256, 0, stream>>>(xn, wk, kb, nullptr, MROWS, D_MODEL, D_MODEL);
    gemm_bt<0><<<gproj, 256, 0, stream>>>(xn, wv, vb, nullptr, MROWS, D_MODEL, D_MODEL);
    attn_k<<<dim3(SEQ / 128, BATCH * NHEAD), 256, 0, stream>>>(qb, kb, vb, ab);
    gemm_bt<2><<<gproj, 256, 0, stream>>>(ab, wo, out, x, MROWS, D_MODEL, D_MODEL);
    rmsnorm_k<<<MROWS, 256, 0, stream>>>(out, g2, xn);
    for (int half = 0; half < 2; ++half) {
      const short* xh = xn  + (size_t)half * 2048 * D_MODEL;
      float*       oh = out + (size_t)half * 2048 * D_MODEL;
      gemm_bt<1><<<dim3(2048 / 128, DFF / 128), 256, 0, stream>>>(xh, w1, hb, nullptr, 2048, DFF, D_MODEL);
      gemm_bt<2><<<dim3(2048 / 128, D_MODEL / 128), 256, 0, stream>>>(hb, w2, oh, oh, 2048, D_MODEL, DFF);
    }
  }
}